// Round 6
// baseline (726.709 us; speedup 1.0000x reference)
//
#include <hip/hip_runtime.h>
#include <hip/hip_bf16.h>
#include <math.h>

#define N_NODES 100000
#define N_RELS 16
#define N_EDGES 1600000
#define OUTW 136   // 64+32+16+16+8
#define NEG_SLOPE 0.01f
#define RES ((size_t)N_NODES * OUTW)

typedef __attribute__((ext_vector_type(8))) short short8;           // 8 bf16 (4 VGPR)
typedef __attribute__((ext_vector_type(8))) unsigned short ushort8;
typedef __attribute__((ext_vector_type(4))) float f32x4;

__device__ __forceinline__ float lrelu(float x) { return x >= 0.f ? x : NEG_SLOPE * x; }
__device__ __forceinline__ float fast_rcp(float x) { return __builtin_amdgcn_rcpf(x); }
__device__ __forceinline__ float fast_tanh(float x) {
    float e = __expf(2.f * x);
    return 1.f - 2.f * fast_rcp(e + 1.f);
}
__device__ __forceinline__ float bf1(unsigned short u) { union { unsigned u; float f; } v; v.u = ((unsigned)u) << 16; return v.f; }
__device__ __forceinline__ unsigned short f2bf(float f) {
    union { float f; unsigned u; } v; v.f = f;
    unsigned x = v.u + 0x7FFF + ((v.u >> 16) & 1);
    return (unsigned short)(x >> 16);
}

// ---------------- CSR offsets over sorted dst ----------------
__global__ void k_offsets(const int* __restrict__ dst, int* __restrict__ offs) {
    int n = blockIdx.x * blockDim.x + threadIdx.x;
    if (n > N_NODES) return;
    int lo = 0, hi = N_EDGES;
    while (lo < hi) { int mid = (lo + hi) >> 1; if (dst[mid] < n) lo = mid + 1; else hi = mid; }
    offs[n] = lo;
}

// ---------------- etype bucketing ----------------
__global__ void k_zero(int* __restrict__ cnt) { if (threadIdx.x < 16) cnt[threadIdx.x] = 0; }

__global__ __launch_bounds__(256) void k_hist(const int* __restrict__ etype, int* __restrict__ cnt) {
    __shared__ int lcnt[16];
    int tid = threadIdx.x;
    if (tid < 16) lcnt[tid] = 0;
    __syncthreads();
    atomicAdd(&lcnt[etype[blockIdx.x * 256 + tid]], 1);
    __syncthreads();
    if (tid < 16 && lcnt[tid]) atomicAdd(&cnt[tid], lcnt[tid]);
}

__global__ void k_scan(const int* __restrict__ cnt, int* __restrict__ roff, int* __restrict__ cur) {
    if (threadIdx.x == 0) {
        int a = 0;
        for (int r = 0; r < 16; ++r) { roff[r] = a; cur[r] = a; a += cnt[r]; }
        roff[16] = a;
    }
}

// scatter edge ids AND permuted src/dst copies (contiguous reads in the att pass)
__global__ __launch_bounds__(256) void k_scatter(const int* __restrict__ etype,
                                                 const int* __restrict__ src,
                                                 const int* __restrict__ dst,
                                                 int* __restrict__ cur, int* __restrict__ eperm,
                                                 int* __restrict__ srcp, int* __restrict__ dstp) {
    __shared__ int lcnt[16], lbase[16], loff[16];
    int tid = threadIdx.x;
    if (tid < 16) { lcnt[tid] = 0; loff[tid] = 0; }
    __syncthreads();
    int e = blockIdx.x * 256 + tid;
    int t = etype[e];
    atomicAdd(&lcnt[t], 1);
    __syncthreads();
    if (tid < 16) lbase[tid] = lcnt[tid] ? atomicAdd(&cur[tid], lcnt[tid]) : 0;
    __syncthreads();
    int rank = atomicAdd(&loff[t], 1);
    int pos = lbase[t] + rank;
    eperm[pos] = e;
    srcp[pos] = src[e];
    dstp[pos] = dst[e];
}

// ---------------- precasts ----------------
__global__ __launch_bounds__(256) void k_cast_emb(const float* __restrict__ emb, unsigned short* __restrict__ embB) {
    int id = blockIdx.x * 256 + threadIdx.x;          // 1.6M float4 slots
    float4 v = *(const float4*)(emb + (size_t)id * 4);
    ushort4 o; o.x = f2bf(v.x); o.y = f2bf(v.y); o.z = f2bf(v.z); o.w = f2bf(v.w);
    *(ushort4*)(embB + (size_t)id * 4) = o;
}

// W_R[r][k][n] fp32 -> WT[r][n][k] bf16
__global__ __launch_bounds__(256) void k_prep_wr(const float* __restrict__ WR, unsigned short* __restrict__ WT) {
    int id = blockIdx.x * 256 + threadIdx.x;          // 65536
    int r = id >> 12, rem = id & 4095, n = rem >> 6, k = rem & 63;
    WT[id] = f2bf(WR[(r << 12) + (k << 6) + n]);
}

// layer weights fp32 transposed [c][k]; L0@0(32x64) L1@2048(16x32) L2@2560(16x16) L3@2816(8x16)
__global__ __launch_bounds__(256) void k_prep_wl(const float* __restrict__ W0, const float* __restrict__ W1,
                                                 const float* __restrict__ W2, const float* __restrict__ W3,
                                                 float* __restrict__ WLT) {
    int id = blockIdx.x * 256 + threadIdx.x;
    if (id >= 2944) return;
    float v;
    if (id < 2048)      { int c = id >> 6, k = id & 63;                  v = W0[k * 32 + c]; }
    else if (id < 2560) { int r = id - 2048; int c = r >> 5, k = r & 31; v = W1[k * 16 + c]; }
    else if (id < 2816) { int r = id - 2560; int c = r >> 4, k = r & 15; v = W2[k * 16 + c]; }
    else                { int r = id - 2816; int c = r >> 4, k = r & 15; v = W3[k * 8 + c]; }
    WLT[id] = v;
}

// ---------------- MFMA GEMM: bufs[cr] = embB @ W_R[c0+cr]  (bf16 in/out) ----------------
__global__ __launch_bounds__(256) void k_gemm_mfma(const unsigned short* __restrict__ embB,
                                                   const unsigned short* __restrict__ WT,   // pre-offset by c0
                                                   unsigned short* __restrict__ bufs, int nrel) {
    int tid = threadIdx.x, w = tid >> 6, l = tid & 63;
    int row0 = blockIdx.x * 128 + w * 32;
    int rlo = l & 15, rhi = l >> 4;

    short8 a[2][2];
    #pragma unroll
    for (int rb = 0; rb < 2; ++rb)
        #pragma unroll
        for (int ks = 0; ks < 2; ++ks) {
            int r = row0 + rb * 16 + rlo;
            if (r >= N_NODES) r = N_NODES - 1;
            a[rb][ks] = *(const short8*)(embB + (size_t)r * 64 + ks * 32 + rhi * 8);
        }

    for (int cr = 0; cr < nrel; ++cr) {
        const unsigned short* wt = WT + ((size_t)cr << 12);
        f32x4 acc[2][4];
        #pragma unroll
        for (int rb = 0; rb < 2; ++rb)
            #pragma unroll
            for (int cb = 0; cb < 4; ++cb) acc[rb][cb] = (f32x4){0.f, 0.f, 0.f, 0.f};
        #pragma unroll
        for (int cb = 0; cb < 4; ++cb) {
            short8 b0 = *(const short8*)(wt + (cb * 16 + rlo) * 64 + rhi * 8);
            short8 b1 = *(const short8*)(wt + (cb * 16 + rlo) * 64 + 32 + rhi * 8);
            acc[0][cb] = __builtin_amdgcn_mfma_f32_16x16x32_bf16(a[0][0], b0, acc[0][cb], 0, 0, 0);
            acc[0][cb] = __builtin_amdgcn_mfma_f32_16x16x32_bf16(a[0][1], b1, acc[0][cb], 0, 0, 0);
            acc[1][cb] = __builtin_amdgcn_mfma_f32_16x16x32_bf16(a[1][0], b0, acc[1][cb], 0, 0, 0);
            acc[1][cb] = __builtin_amdgcn_mfma_f32_16x16x32_bf16(a[1][1], b1, acc[1][cb], 0, 0, 0);
        }
        unsigned short* ob = bufs + (size_t)cr * N_NODES * 64;
        #pragma unroll
        for (int rb = 0; rb < 2; ++rb)
            #pragma unroll
            for (int cb = 0; cb < 4; ++cb)
                #pragma unroll
                for (int i = 0; i < 4; ++i) {
                    int gr = row0 + rb * 16 + rhi * 4 + i;
                    if (gr < N_NODES) ob[(size_t)gr * 64 + cb * 16 + rlo] = f2bf(acc[rb][cb][i]);
                }
    }
}

// ---------------- attention over chunk [c0, c0+nc): 8 lanes/edge, 8 edges/wave ----------------
__global__ __launch_bounds__(256) void k_edge_att4(const unsigned short* __restrict__ bufs,
                                                   const float* __restrict__ rel,
                                                   const int* __restrict__ srcp,
                                                   const int* __restrict__ dstp,
                                                   const int* __restrict__ eperm,
                                                   const int* __restrict__ roff,
                                                   int c0, int nc, float* __restrict__ att) {
    int lo = roff[c0];
    int cnt = roff[c0 + nc] - lo;
    int bnd0 = (nc > 1) ? roff[c0 + 1] - lo : 0x7fffffff;
    int bnd1 = (nc > 2) ? roff[c0 + 2] - lo : 0x7fffffff;
    int bnd2 = (nc > 3) ? roff[c0 + 3] - lo : 0x7fffffff;
    int tid = threadIdx.x, lane = tid & 63;
    int sub = lane >> 3, lj = lane & 7, d0 = lj * 8;
    int gw = (blockIdx.x * 256 + tid) >> 6;
    int nw = (gridDim.x * 256) >> 6;
    for (int i = gw * 8 + sub; i < cnt; i += nw * 8) {
        int t = (i >= bnd0) + (i >= bnd1) + (i >= bnd2);
        const unsigned short* bb = bufs + (size_t)t * N_NODES * 64;
        const float* rr = rel + (size_t)(c0 + t) * 64 + d0;
        size_t s = (size_t)srcp[lo + i], dn = (size_t)dstp[lo + i];
        ushort8 tv = *(const ushort8*)(bb + s * 64 + d0);
        ushort8 hv = *(const ushort8*)(bb + dn * 64 + d0);
        float4 r0 = *(const float4*)(rr);
        float4 r1 = *(const float4*)(rr + 4);
        float v = bf1(tv[0]) * fast_tanh(bf1(hv[0]) + r0.x)
                + bf1(tv[1]) * fast_tanh(bf1(hv[1]) + r0.y)
                + bf1(tv[2]) * fast_tanh(bf1(hv[2]) + r0.z)
                + bf1(tv[3]) * fast_tanh(bf1(hv[3]) + r0.w)
                + bf1(tv[4]) * fast_tanh(bf1(hv[4]) + r1.x)
                + bf1(tv[5]) * fast_tanh(bf1(hv[5]) + r1.y)
                + bf1(tv[6]) * fast_tanh(bf1(hv[6]) + r1.z)
                + bf1(tv[7]) * fast_tanh(bf1(hv[7]) + r1.w);
        #pragma unroll
        for (int m = 1; m < 8; m <<= 1) v += __shfl_xor(v, m);
        if (lj == 0) att[eperm[lo + i]] = v;
    }
}

// ---------------- per-dst softmax, 8 lanes per node ----------------
__global__ __launch_bounds__(256) void k_softmax(float* __restrict__ att, const int* __restrict__ offs) {
    int tid = threadIdx.x;
    int n = blockIdx.x * 32 + (tid >> 3);
    int j = tid & 7;
    int b = offs[n], e = offs[n + 1];
    if (b >= e) return;
    float m = -INFINITY;
    for (int i = b + j; i < e; i += 8) m = fmaxf(m, att[i]);
    #pragma unroll
    for (int s = 4; s >= 1; s >>= 1) m = fmaxf(m, __shfl_xor(m, s));
    float sum = 0.f;
    for (int i = b + j; i < e; i += 8) { float v = __expf(att[i] - m); att[i] = v; sum += v; }
    #pragma unroll
    for (int s = 4; s >= 1; s >>= 1) sum += __shfl_xor(sum, s);
    float inv = fast_rcp(sum);
    for (int i = b + j; i < e; i += 8) att[i] *= inv;
}

// ---------------- layer-1 fused agg: fp32 gathers, 4 slots x unroll-4 (16 gathers in flight) ----------------
__global__ __launch_bounds__(256) void k_agg1(const float* __restrict__ emb,
                                              const float* __restrict__ att,
                                              const int* __restrict__ src,
                                              const int* __restrict__ offs,
                                              const float* __restrict__ WLT,   // W0T [32][64]
                                              const float* __restrict__ bias,
                                              float* __restrict__ U1,
                                              float* __restrict__ out) {
    __shared__ float xm[4][64];
    int tid = threadIdx.x, w = tid >> 6, l = tid & 63;
    int n = blockIdx.x * 4 + w;
    int b = offs[n], e = offs[n + 1];
    int j = l & 15, slot = l >> 4;      // 16 lanes/edge (float4 each), 4 edge slots
    int c = l & 31, g = l >> 5;         // matmul mapping

    float Wreg[32];
    #pragma unroll
    for (int kk = 0; kk < 32; ++kk) Wreg[kk] = WLT[(size_t)c * 64 + g * 32 + kk];

    float a0 = 0.f, a1 = 0.f, a2 = 0.f, a3 = 0.f;
    int i = b + slot;
    for (; i + 12 < e; i += 16) {       // 4 independent gathers in flight
        float t0 = att[i], t1 = att[i + 4], t2 = att[i + 8], t3 = att[i + 12];
        float4 p0 = *(const float4*)(emb + (size_t)src[i]      * 64 + 4 * j);
        float4 p1 = *(const float4*)(emb + (size_t)src[i + 4]  * 64 + 4 * j);
        float4 p2 = *(const float4*)(emb + (size_t)src[i + 8]  * 64 + 4 * j);
        float4 p3 = *(const float4*)(emb + (size_t)src[i + 12] * 64 + 4 * j);
        a0 += t0 * p0.x + t1 * p1.x + t2 * p2.x + t3 * p3.x;
        a1 += t0 * p0.y + t1 * p1.y + t2 * p2.y + t3 * p3.y;
        a2 += t0 * p0.z + t1 * p1.z + t2 * p2.z + t3 * p3.z;
        a3 += t0 * p0.w + t1 * p1.w + t2 * p2.w + t3 * p3.w;
    }
    for (; i + 4 < e; i += 8) {
        float t0 = att[i], t1 = att[i + 4];
        float4 p0 = *(const float4*)(emb + (size_t)src[i]     * 64 + 4 * j);
        float4 p1 = *(const float4*)(emb + (size_t)src[i + 4] * 64 + 4 * j);
        a0 += t0 * p0.x + t1 * p1.x;
        a1 += t0 * p0.y + t1 * p1.y;
        a2 += t0 * p0.z + t1 * p1.z;
        a3 += t0 * p0.w + t1 * p1.w;
    }
    for (; i < e; i += 4) {
        float t0 = att[i];
        float4 p0 = *(const float4*)(emb + (size_t)src[i] * 64 + 4 * j);
        a0 += t0 * p0.x; a1 += t0 * p0.y; a2 += t0 * p0.z; a3 += t0 * p0.w;
    }
    #pragma unroll
    for (int st = 16; st < 64; st <<= 1) {
        a0 += __shfl_xor(a0, st); a1 += __shfl_xor(a1, st);
        a2 += __shfl_xor(a2, st); a3 += __shfl_xor(a3, st);
    }
    if (l < 16) {
        float4 q = *(const float4*)(emb + (size_t)n * 64 + 4 * j);
        *(float4*)&xm[w][4 * j] = make_float4(a0 + q.x, a1 + q.y, a2 + q.z, a3 + q.w);
    }
    __builtin_amdgcn_s_waitcnt(0);
    __builtin_amdgcn_sched_barrier(0);

    float o = 0.f;
    #pragma unroll
    for (int kk = 0; kk < 32; kk += 4) {
        float4 xv = *(const float4*)&xm[w][g * 32 + kk];
        o += xv.x * Wreg[kk] + xv.y * Wreg[kk + 1] + xv.z * Wreg[kk + 2] + xv.w * Wreg[kk + 3];
    }
    o += __shfl_xor(o, 32);

    float u = 0.f;
    if (l < 32) {
        u = lrelu(o + bias[l]);
        U1[(size_t)n * 32 + l] = u;
    }
    float ss = u * u;
    #pragma unroll
    for (int m = 16; m >= 1; m >>= 1) ss += __shfl_xor(ss, m);
    if (l < 32) {
        float nrm = u * fast_rcp(fmaxf(sqrtf(ss), 1e-12f));
        #pragma unroll
        for (int rr = 0; rr < 4; ++rr)
            out[(size_t)rr * RES + (size_t)n * OUTW + 64 + l] = nrm;
    }
}

// ---------------- fused aggregate + layer + norm-broadcast (fp32, U-chain), deep-pipelined ----------------
template<int DIN, int DOUT, int COL, int RSTART, bool WU>
__global__ __launch_bounds__(256) void k_agg(const float* __restrict__ x,
                                             const float* __restrict__ att,
                                             const int* __restrict__ src,
                                             const int* __restrict__ offs,
                                             const float* __restrict__ WLT,
                                             const float* __restrict__ bias,
                                             float* __restrict__ Un,
                                             float* __restrict__ out) {
    constexpr int L = DIN / 2;        // lanes per edge (float2 each)
    constexpr int S = 64 / L;         // edge slots per wave
    constexpr int G = 64 / DOUT;      // k-groups for matmul
    constexpr int KS = DIN / G;       // k-slice per lane
    __shared__ float xm[4][DIN];
    int tid = threadIdx.x, w = tid >> 6, l = tid & 63;
    int n = blockIdx.x * 4 + w;
    int b = offs[n], e = offs[n + 1];
    int j = l & (L - 1), slot = l / L;
    int c = l & (DOUT - 1), g = l / DOUT;

    float Wreg[KS];
    #pragma unroll
    for (int kk = 0; kk < KS; ++kk) Wreg[kk] = WLT[(size_t)c * DIN + g * KS + kk];

    float ax = 0.f, ay = 0.f;
    int i = b + slot;
    if constexpr (S == 4) {           // DIN=32: 4 slots -> unroll 4 (16 edges in flight)
        for (; i + 3 * S < e; i += 4 * S) {
            float t0 = att[i], t1 = att[i + S], t2 = att[i + 2 * S], t3 = att[i + 3 * S];
            float2 p0 = *(const float2*)(x + (size_t)src[i]         * DIN + 2 * j);
            float2 p1 = *(const float2*)(x + (size_t)src[i + S]     * DIN + 2 * j);
            float2 p2 = *(const float2*)(x + (size_t)src[i + 2 * S] * DIN + 2 * j);
            float2 p3 = *(const float2*)(x + (size_t)src[i + 3 * S] * DIN + 2 * j);
            ax += t0 * p0.x + t1 * p1.x + t2 * p2.x + t3 * p3.x;
            ay += t0 * p0.y + t1 * p1.y + t2 * p2.y + t3 * p3.y;
        }
    }
    for (; i + S < e; i += 2 * S) {   // unroll 2
        float t0 = att[i], t1 = att[i + S];
        float2 p0 = *(const float2*)(x + (size_t)src[i]     * DIN + 2 * j);
        float2 p1 = *(const float2*)(x + (size_t)src[i + S] * DIN + 2 * j);
        ax += t0 * p0.x + t1 * p1.x;
        ay += t0 * p0.y + t1 * p1.y;
    }
    for (; i < e; i += S) {
        float t0 = att[i];
        float2 p0 = *(const float2*)(x + (size_t)src[i] * DIN + 2 * j);
        ax += t0 * p0.x; ay += t0 * p0.y;
    }
    #pragma unroll
    for (int st = L; st < 64; st <<= 1) { ax += __shfl_xor(ax, st); ay += __shfl_xor(ay, st); }
    if (l < L) {
        float2 q = *(const float2*)(x + (size_t)n * DIN + 2 * j);
        *(float2*)&xm[w][2 * j] = make_float2(ax + q.x, ay + q.y);
    }
    __builtin_amdgcn_s_waitcnt(0);
    __builtin_amdgcn_sched_barrier(0);

    float o = 0.f;
    if constexpr (KS >= 4) {
        #pragma unroll
        for (int kk = 0; kk < KS; kk += 4) {
            float4 xv = *(const float4*)&xm[w][g * KS + kk];
            o += xv.x * Wreg[kk] + xv.y * Wreg[kk + 1] + xv.z * Wreg[kk + 2] + xv.w * Wreg[kk + 3];
        }
    } else {
        float2 xv = *(const float2*)&xm[w][g * KS];
        o += xv.x * Wreg[0] + xv.y * Wreg[1];
    }
    #pragma unroll
    for (int st = DOUT; st < 64; st <<= 1) o += __shfl_xor(o, st);

    float u = 0.f;
    if (l < DOUT) {
        u = lrelu(o + bias[l]);
        if (WU) Un[(size_t)n * DOUT + l] = u;
    }
    float ss = u * u;
    #pragma unroll
    for (int m = DOUT / 2; m >= 1; m >>= 1) ss += __shfl_xor(ss, m);
    if (l < DOUT) {
        float nrm = u * fast_rcp(fmaxf(sqrtf(ss), 1e-12f));
        #pragma unroll
        for (int rr = RSTART; rr < 4; ++rr)
            out[(size_t)rr * RES + (size_t)n * OUTW + COL + l] = nrm;
    }
}

// ---------------- all B-chains in ONE dispatch (LDS-resident intermediates) ----------------
__global__ __launch_bounds__(256) void k_bchain(const float* __restrict__ U1,
                                                const float* __restrict__ U2,
                                                const float* __restrict__ U3,
                                                const float* __restrict__ WLT,
                                                const float* __restrict__ b1,
                                                const float* __restrict__ b2,
                                                const float* __restrict__ b3,
                                                float* __restrict__ out) {
    __shared__ float W1s[16][33], W2s[16][17], W3s[8][17];
    __shared__ float bb1[16], bb2[16], bb3[8];
    __shared__ float row[16][33], mid[16][17], mid2[16][17];
    int tid = threadIdx.x;
    for (int id = tid; id < 512; id += 256) W1s[id >> 5][id & 31] = WLT[2048 + id];
    { int id = tid; if (id < 256) W2s[id >> 4][id & 15] = WLT[2560 + id]; }
    if (tid < 128) W3s[tid >> 4][tid & 15] = WLT[2816 + tid];
    if (tid < 16) bb1[tid] = b1[tid];
    if (tid >= 32 && tid < 48) bb2[tid - 32] = b2[tid - 32];
    if (tid >= 64 && tid < 72) bb3[tid - 64] = b3[tid - 64];
    __syncthreads();

    int grp = tid >> 4, lj = tid & 15;
    int seg = blockIdx.x / 6250;
    int nb = blockIdx.x % 6250;
    int n = nb * 16 + grp;

    if (seg == 0) {
        *(float2*)&row[grp][2 * lj] = *(const float2*)(U1 + (size_t)n * 32 + 2 * lj);
        __builtin_amdgcn_s_waitcnt(0);
        __builtin_amdgcn_sched_barrier(0);
        float o1 = bb1[lj];
        #pragma unroll
        for (int k = 0; k < 32; ++k) o1 += row[grp][k] * W1s[lj][k];
        float u1 = lrelu(o1);
        mid[grp][lj] = u1;
        float ss = u1 * u1;
        #pragma unroll
        for (int m = 8; m >= 1; m >>= 1) ss += __shfl_xor(ss, m);
        out[(size_t)n * OUTW + 96 + lj] = u1 * fast_rcp(fmaxf(sqrtf(ss), 1e-12f));
        __builtin_amdgcn_s_waitcnt(0);
        __builtin_amdgcn_sched_barrier(0);
        float o2 = bb2[lj];
        #pragma unroll
        for (int k = 0; k < 16; ++k) o2 += mid[grp][k] * W2s[lj][k];
        float u2 = lrelu(o2);
        mid2[grp][lj] = u2;
        float s2 = u2 * u2;
        #pragma unroll
        for (int m = 8; m >= 1; m >>= 1) s2 += __shfl_xor(s2, m);
        out[(size_t)n * OUTW + 112 + lj] = u2 * fast_rcp(fmaxf(sqrtf(s2), 1e-12f));
        __builtin_amdgcn_s_waitcnt(0);
        __builtin_amdgcn_sched_barrier(0);
        if (lj < 8) {
            float o3 = bb3[lj];
            #pragma unroll
            for (int k = 0; k < 16; ++k) o3 += mid2[grp][k] * W3s[lj][k];
            float u3 = lrelu(o3);
            float s3 = u3 * u3;
            #pragma unroll
            for (int m = 4; m >= 1; m >>= 1) s3 += __shfl_xor(s3, m);
            out[(size_t)n * OUTW + 128 + lj] = u3 * fast_rcp(fmaxf(sqrtf(s3), 1e-12f));
        }
    } else if (seg == 1) {
        mid[grp][lj] = U2[(size_t)n * 16 + lj];
        __builtin_amdgcn_s_waitcnt(0);
        __builtin_amdgcn_sched_barrier(0);
        float o2 = bb2[lj];
        #pragma unroll
        for (int k = 0; k < 16; ++k) o2 += mid[grp][k] * W2s[lj][k];
        float u2 = lrelu(o2);
        mid2[grp][lj] = u2;
        float s2 = u2 * u2;
        #pragma unroll
        for (int m = 8; m >= 1; m >>= 1) s2 += __shfl_xor(s2, m);
        out[RES + (size_t)n * OUTW + 112 + lj] = u2 * fast_rcp(fmaxf(sqrtf(s2), 1e-12f));
        __builtin_amdgcn_s_waitcnt(0);
        __builtin_amdgcn_sched_barrier(0);
        if (lj < 8) {
            float o3 = bb3[lj];
            #pragma unroll
            for (int k = 0; k < 16; ++k) o3 += mid2[grp][k] * W3s[lj][k];
            float u3 = lrelu(o3);
            float s3 = u3 * u3;
            #pragma unroll
            for (int m = 4; m >= 1; m >>= 1) s3 += __shfl_xor(s3, m);
            out[RES + (size_t)n * OUTW + 128 + lj] = u3 * fast_rcp(fmaxf(sqrtf(s3), 1e-12f));
        }
    } else {
        mid[grp][lj] = U3[(size_t)n * 16 + lj];
        __builtin_amdgcn_s_waitcnt(0);
        __builtin_amdgcn_sched_barrier(0);
        if (lj < 8) {
            float o3 = bb3[lj];
            #pragma unroll
            for (int k = 0; k < 16; ++k) o3 += mid[grp][k] * W3s[lj][k];
            float u3 = lrelu(o3);
            float s3 = u3 * u3;
            #pragma unroll
            for (int m = 4; m >= 1; m >>= 1) s3 += __shfl_xor(s3, m);
            out[2 * RES + (size_t)n * OUTW + 128 + lj] = u3 * fast_rcp(fmaxf(sqrtf(s3), 1e-12f));
        }
    }
}

// ---------------- emb block copy to all 4 results ----------------
__global__ __launch_bounds__(256) void k_emb_copy(const float* __restrict__ emb, float* __restrict__ out) {
    int idx = blockIdx.x * 256 + threadIdx.x;
    int n = idx >> 4, cc = (idx & 15) * 4;
    float4 v = *(const float4*)(emb + (size_t)n * 64 + cc);
    #pragma unroll
    for (int r = 0; r < 4; ++r)
        *(float4*)(out + (size_t)r * RES + (size_t)n * OUTW + cc) = v;
}

extern "C" void kernel_launch(void* const* d_in, const int* in_sizes, int n_in,
                              void* d_out, int out_size, void* d_ws, size_t ws_size,
                              hipStream_t stream) {
    (void)in_sizes; (void)n_in; (void)out_size;
    const float* emb = (const float*)d_in[0];
    const float* rel_embed = (const float*)d_in[1];
    const float* W_R = (const float*)d_in[2];
    const float* W0 = (const float*)d_in[3];  const float* b0 = (const float*)d_in[4];
    const float* W1 = (const float*)d_in[5];  const float* b1 = (const float*)d_in[6];
    const float* W2 = (const float*)d_in[7];  const float* b2 = (const float*)d_in[8];
    const float* W3 = (const float*)d_in[9];  const float* b3 = (const float*)d_in[10];
    const int* src = (const int*)d_in[11];
    const int* dst = (const int*)d_in[12];
    const int* etype = (const int*)d_in[13];
    float* out = (float*)d_out;

    char* p = (char*)d_ws;
    auto alloc = [&](size_t bytes) { char* q = p; p += (bytes + 255) & ~(size_t)255; return q; };
    int* offs  = (int*)alloc((size_t)(N_NODES + 1) * 4);
    float* att = (float*)alloc((size_t)N_EDGES * 4);
    int* eperm = (int*)alloc((size_t)N_EDGES * 4);
    int* srcp  = (int*)alloc((size_t)N_EDGES * 4);
    int* dstp  = (int*)alloc((size_t)N_EDGES * 4);
    int* cnt   = (int*)alloc(64);
    int* roff  = (int*)alloc(68);
    int* cur   = (int*)alloc(64);
    unsigned short* embB = (unsigned short*)alloc((size_t)N_NODES * 64 * 2);
    unsigned short* WT   = (unsigned short*)alloc((size_t)65536 * 2);
    float* WLT  = (float*)alloc((size_t)2944 * 4);
    float* U1   = (float*)alloc((size_t)N_NODES * 32 * 4);
    float* U2   = (float*)alloc((size_t)N_NODES * 16 * 4);
    float* U3   = (float*)alloc((size_t)N_NODES * 16 * 4);
    size_t fixed = (size_t)(p - (char*)d_ws);
    size_t per_rel = (size_t)N_NODES * 64 * 2;   // bf16 buf per relation
    int chunk = 1;
    if (ws_size > fixed + per_rel)
        chunk = (int)((ws_size - fixed) / per_rel);
    if (chunk > 4) chunk = 4;                    // keep footprint L2/L3-resident
    if (chunk < 1) chunk = 1;
    unsigned short* allbuf = (unsigned short*)p;

    // prep
    k_offsets<<<(N_NODES + 256) / 256, 256, 0, stream>>>(dst, offs);
    k_zero<<<1, 64, 0, stream>>>(cnt);
    k_hist<<<N_EDGES / 256, 256, 0, stream>>>(etype, cnt);
    k_scan<<<1, 64, 0, stream>>>(cnt, roff, cur);
    k_scatter<<<N_EDGES / 256, 256, 0, stream>>>(etype, src, dst, cur, eperm, srcp, dstp);
    k_cast_emb<<<N_NODES * 16 / 256, 256, 0, stream>>>(emb, embB);
    k_prep_wr<<<256, 256, 0, stream>>>(W_R, WT);
    k_prep_wl<<<12, 256, 0, stream>>>(W0, W1, W2, W3, WLT);

    // attention: chunked MFMA transform + edge scores (bufs stay cache-resident)
    for (int c0 = 0; c0 < N_RELS; c0 += chunk) {
        int nc = N_RELS - c0 < chunk ? N_RELS - c0 : chunk;
        k_gemm_mfma<<<(N_NODES + 127) / 128, 256, 0, stream>>>(embB, WT + (size_t)c0 * 4096, allbuf, nc);
        k_edge_att4<<<2048, 256, 0, stream>>>(allbuf, rel_embed, srcp, dstp, eperm, roff, c0, nc, att);
    }
    k_softmax<<<N_NODES / 32, 256, 0, stream>>>(att, offs);

    // A-chain
    k_agg1<<<N_NODES / 4, 256, 0, stream>>>(emb, att, src, offs, WLT, b0, U1, out);
    k_agg<32, 16, 96, 1, true ><<<N_NODES / 4, 256, 0, stream>>>(U1, att, src, offs, WLT + 2048, b1, U2, out);
    k_agg<16, 16, 112, 2, true><<<N_NODES / 4, 256, 0, stream>>>(U2, att, src, offs, WLT + 2560, b2, U3, out);
    k_agg<16, 8, 128, 3, false><<<N_NODES / 4, 256, 0, stream>>>(U3, att, src, offs, WLT + 2816, b3, nullptr, out);

    // all B-chains, one dispatch
    k_bchain<<<18750, 256, 0, stream>>>(U1, U2, U3, WLT, b1, b2, b3, out);

    // emb block
    k_emb_copy<<<N_NODES * 16 / 256, 256, 0, stream>>>(emb, out);
}

// Round 7
// 648.682 us; speedup vs baseline: 1.1203x; 1.1203x over previous
//
#include <hip/hip_runtime.h>
#include <hip/hip_bf16.h>
#include <math.h>

#define N_NODES 100000
#define N_RELS 16
#define N_EDGES 1600000
#define OUTW 136   // 64+32+16+16+8
#define NEG_SLOPE 0.01f
#define RES ((size_t)N_NODES * OUTW)

typedef __attribute__((ext_vector_type(8))) short short8;           // 8 bf16 (4 VGPR)
typedef __attribute__((ext_vector_type(8))) unsigned short ushort8;
typedef __attribute__((ext_vector_type(4))) float f32x4;

__device__ __forceinline__ float lrelu(float x) { return x >= 0.f ? x : NEG_SLOPE * x; }
__device__ __forceinline__ float fast_rcp(float x) { return __builtin_amdgcn_rcpf(x); }
__device__ __forceinline__ float fast_tanh(float x) {
    float e = __expf(2.f * x);
    return 1.f - 2.f * fast_rcp(e + 1.f);
}
__device__ __forceinline__ float bf1(unsigned short u) { union { unsigned u; float f; } v; v.u = ((unsigned)u) << 16; return v.f; }
__device__ __forceinline__ unsigned short f2bf(float f) {
    union { float f; unsigned u; } v; v.f = f;
    unsigned x = v.u + 0x7FFF + ((v.u >> 16) & 1);
    return (unsigned short)(x >> 16);
}

// ---------------- CSR offsets over sorted dst ----------------
__global__ void k_offsets(const int* __restrict__ dst, int* __restrict__ offs) {
    int n = blockIdx.x * blockDim.x + threadIdx.x;
    if (n > N_NODES) return;
    int lo = 0, hi = N_EDGES;
    while (lo < hi) { int mid = (lo + hi) >> 1; if (dst[mid] < n) lo = mid + 1; else hi = mid; }
    offs[n] = lo;
}

// ---------------- etype bucketing ----------------
__global__ void k_zero(int* __restrict__ cnt) { if (threadIdx.x < 16) cnt[threadIdx.x] = 0; }

__global__ __launch_bounds__(256) void k_hist(const int* __restrict__ etype, int* __restrict__ cnt) {
    __shared__ int lcnt[16];
    int tid = threadIdx.x;
    if (tid < 16) lcnt[tid] = 0;
    __syncthreads();
    atomicAdd(&lcnt[etype[blockIdx.x * 256 + tid]], 1);
    __syncthreads();
    if (tid < 16 && lcnt[tid]) atomicAdd(&cnt[tid], lcnt[tid]);
}

__global__ void k_scan(const int* __restrict__ cnt, int* __restrict__ roff, int* __restrict__ cur) {
    if (threadIdx.x == 0) {
        int a = 0;
        for (int r = 0; r < 16; ++r) { roff[r] = a; cur[r] = a; a += cnt[r]; }
        roff[16] = a;
    }
}

// scatter edge ids AND permuted src/dst copies (contiguous reads in the att pass)
__global__ __launch_bounds__(256) void k_scatter(const int* __restrict__ etype,
                                                 const int* __restrict__ src,
                                                 const int* __restrict__ dst,
                                                 int* __restrict__ cur, int* __restrict__ eperm,
                                                 int* __restrict__ srcp, int* __restrict__ dstp) {
    __shared__ int lcnt[16], lbase[16], loff[16];
    int tid = threadIdx.x;
    if (tid < 16) { lcnt[tid] = 0; loff[tid] = 0; }
    __syncthreads();
    int e = blockIdx.x * 256 + tid;
    int t = etype[e];
    atomicAdd(&lcnt[t], 1);
    __syncthreads();
    if (tid < 16) lbase[tid] = lcnt[tid] ? atomicAdd(&cur[tid], lcnt[tid]) : 0;
    __syncthreads();
    int rank = atomicAdd(&loff[t], 1);
    int pos = lbase[t] + rank;
    eperm[pos] = e;
    srcp[pos] = src[e];
    dstp[pos] = dst[e];
}

// ---------------- precasts ----------------
__global__ __launch_bounds__(256) void k_cast_emb(const float* __restrict__ emb, unsigned short* __restrict__ embB) {
    int id = blockIdx.x * 256 + threadIdx.x;          // 1.6M float4 slots
    float4 v = *(const float4*)(emb + (size_t)id * 4);
    ushort4 o; o.x = f2bf(v.x); o.y = f2bf(v.y); o.z = f2bf(v.z); o.w = f2bf(v.w);
    *(ushort4*)(embB + (size_t)id * 4) = o;
}

// W_R[r][k][n] fp32 -> WT[r][n][k] bf16
__global__ __launch_bounds__(256) void k_prep_wr(const float* __restrict__ WR, unsigned short* __restrict__ WT) {
    int id = blockIdx.x * 256 + threadIdx.x;          // 65536
    int r = id >> 12, rem = id & 4095, n = rem >> 6, k = rem & 63;
    WT[id] = f2bf(WR[(r << 12) + (k << 6) + n]);
}

// layer weights fp32 transposed [c][k]; L0@0(32x64) L1@2048(16x32) L2@2560(16x16) L3@2816(8x16)
__global__ __launch_bounds__(256) void k_prep_wl(const float* __restrict__ W0, const float* __restrict__ W1,
                                                 const float* __restrict__ W2, const float* __restrict__ W3,
                                                 float* __restrict__ WLT) {
    int id = blockIdx.x * 256 + threadIdx.x;
    if (id >= 2944) return;
    float v;
    if (id < 2048)      { int c = id >> 6, k = id & 63;                  v = W0[k * 32 + c]; }
    else if (id < 2560) { int r = id - 2048; int c = r >> 5, k = r & 31; v = W1[k * 16 + c]; }
    else if (id < 2816) { int r = id - 2560; int c = r >> 4, k = r & 15; v = W2[k * 16 + c]; }
    else                { int r = id - 2816; int c = r >> 4, k = r & 15; v = W3[k * 8 + c]; }
    WLT[id] = v;
}

// ---------------- MFMA GEMM: bufs[cr] = embB @ W_R[c0+cr]  (bf16 in/out) ----------------
__global__ __launch_bounds__(256) void k_gemm_mfma(const unsigned short* __restrict__ embB,
                                                   const unsigned short* __restrict__ WT,   // pre-offset by c0
                                                   unsigned short* __restrict__ bufs, int nrel) {
    int tid = threadIdx.x, w = tid >> 6, l = tid & 63;
    int row0 = blockIdx.x * 128 + w * 32;
    int rlo = l & 15, rhi = l >> 4;

    short8 a[2][2];
    #pragma unroll
    for (int rb = 0; rb < 2; ++rb)
        #pragma unroll
        for (int ks = 0; ks < 2; ++ks) {
            int r = row0 + rb * 16 + rlo;
            if (r >= N_NODES) r = N_NODES - 1;
            a[rb][ks] = *(const short8*)(embB + (size_t)r * 64 + ks * 32 + rhi * 8);
        }

    for (int cr = 0; cr < nrel; ++cr) {
        const unsigned short* wt = WT + ((size_t)cr << 12);
        f32x4 acc[2][4];
        #pragma unroll
        for (int rb = 0; rb < 2; ++rb)
            #pragma unroll
            for (int cb = 0; cb < 4; ++cb) acc[rb][cb] = (f32x4){0.f, 0.f, 0.f, 0.f};
        #pragma unroll
        for (int cb = 0; cb < 4; ++cb) {
            short8 b0 = *(const short8*)(wt + (cb * 16 + rlo) * 64 + rhi * 8);
            short8 b1 = *(const short8*)(wt + (cb * 16 + rlo) * 64 + 32 + rhi * 8);
            acc[0][cb] = __builtin_amdgcn_mfma_f32_16x16x32_bf16(a[0][0], b0, acc[0][cb], 0, 0, 0);
            acc[0][cb] = __builtin_amdgcn_mfma_f32_16x16x32_bf16(a[0][1], b1, acc[0][cb], 0, 0, 0);
            acc[1][cb] = __builtin_amdgcn_mfma_f32_16x16x32_bf16(a[1][0], b0, acc[1][cb], 0, 0, 0);
            acc[1][cb] = __builtin_amdgcn_mfma_f32_16x16x32_bf16(a[1][1], b1, acc[1][cb], 0, 0, 0);
        }
        unsigned short* ob = bufs + (size_t)cr * N_NODES * 64;
        #pragma unroll
        for (int rb = 0; rb < 2; ++rb)
            #pragma unroll
            for (int cb = 0; cb < 4; ++cb)
                #pragma unroll
                for (int i = 0; i < 4; ++i) {
                    int gr = row0 + rb * 16 + rhi * 4 + i;
                    if (gr < N_NODES) ob[(size_t)gr * 64 + cb * 16 + rlo] = f2bf(acc[rb][cb][i]);
                }
    }
}

// ---------------- attention over chunk [c0, c0+nc): 8 lanes/edge, 8 edges/wave ----------------
__global__ __launch_bounds__(256) void k_edge_att4(const unsigned short* __restrict__ bufs,
                                                   const float* __restrict__ rel,
                                                   const int* __restrict__ srcp,
                                                   const int* __restrict__ dstp,
                                                   const int* __restrict__ eperm,
                                                   const int* __restrict__ roff,
                                                   int c0, int nc, float* __restrict__ att) {
    int lo = roff[c0];
    int cnt = roff[c0 + nc] - lo;
    int bnd0 = (nc > 1) ? roff[c0 + 1] - lo : 0x7fffffff;
    int bnd1 = (nc > 2) ? roff[c0 + 2] - lo : 0x7fffffff;
    int bnd2 = (nc > 3) ? roff[c0 + 3] - lo : 0x7fffffff;
    int tid = threadIdx.x, lane = tid & 63;
    int sub = lane >> 3, lj = lane & 7, d0 = lj * 8;
    int gw = (blockIdx.x * 256 + tid) >> 6;
    int nw = (gridDim.x * 256) >> 6;
    for (int i = gw * 8 + sub; i < cnt; i += nw * 8) {
        int t = (i >= bnd0) + (i >= bnd1) + (i >= bnd2);
        const unsigned short* bb = bufs + (size_t)t * N_NODES * 64;
        const float* rr = rel + (size_t)(c0 + t) * 64 + d0;
        size_t s = (size_t)srcp[lo + i], dn = (size_t)dstp[lo + i];
        ushort8 tv = *(const ushort8*)(bb + s * 64 + d0);
        ushort8 hv = *(const ushort8*)(bb + dn * 64 + d0);
        float4 r0 = *(const float4*)(rr);
        float4 r1 = *(const float4*)(rr + 4);
        float v = bf1(tv[0]) * fast_tanh(bf1(hv[0]) + r0.x)
                + bf1(tv[1]) * fast_tanh(bf1(hv[1]) + r0.y)
                + bf1(tv[2]) * fast_tanh(bf1(hv[2]) + r0.z)
                + bf1(tv[3]) * fast_tanh(bf1(hv[3]) + r0.w)
                + bf1(tv[4]) * fast_tanh(bf1(hv[4]) + r1.x)
                + bf1(tv[5]) * fast_tanh(bf1(hv[5]) + r1.y)
                + bf1(tv[6]) * fast_tanh(bf1(hv[6]) + r1.z)
                + bf1(tv[7]) * fast_tanh(bf1(hv[7]) + r1.w);
        #pragma unroll
        for (int m = 1; m < 8; m <<= 1) v += __shfl_xor(v, m);
        if (lj == 0) att[eperm[lo + i]] = v;
    }
}

// ---------------- per-dst softmax, 8 lanes per node ----------------
__global__ __launch_bounds__(256) void k_softmax(float* __restrict__ att, const int* __restrict__ offs) {
    int tid = threadIdx.x;
    int n = blockIdx.x * 32 + (tid >> 3);
    int j = tid & 7;
    int b = offs[n], e = offs[n + 1];
    if (b >= e) return;
    float m = -INFINITY;
    for (int i = b + j; i < e; i += 8) m = fmaxf(m, att[i]);
    #pragma unroll
    for (int s = 4; s >= 1; s >>= 1) m = fmaxf(m, __shfl_xor(m, s));
    float sum = 0.f;
    for (int i = b + j; i < e; i += 8) { float v = __expf(att[i] - m); att[i] = v; sum += v; }
    #pragma unroll
    for (int s = 4; s >= 1; s >>= 1) sum += __shfl_xor(sum, s);
    float inv = fast_rcp(sum);
    for (int i = b + j; i < e; i += 8) att[i] *= inv;
}

// ---------------- dense projection: y[n] = x[n] @ W  (W pre-transposed [c][k]) ----------------
template<int DIN, int DOUT>
__global__ __launch_bounds__(256) void k_dense(const float* __restrict__ x,
                                               const float* __restrict__ WLTp,
                                               float* __restrict__ y) {
    constexpr int G = 64 / DOUT;      // k-groups
    constexpr int KS = DIN / G;       // k-slice per lane
    int tid = threadIdx.x, w = tid >> 6, l = tid & 63;
    int c = l & (DOUT - 1), g = l / DOUT;

    float Wreg[KS];
    #pragma unroll
    for (int kk = 0; kk < KS; ++kk) Wreg[kk] = WLTp[(size_t)c * DIN + g * KS + kk];

    int nw = gridDim.x * 4;
    for (int n = blockIdx.x * 4 + w; n < N_NODES; n += nw) {
        const float* xr = x + (size_t)n * DIN + g * KS;
        float o = 0.f;
        if constexpr (KS >= 4) {
            #pragma unroll
            for (int kk = 0; kk < KS; kk += 4) {
                float4 xv = *(const float4*)(xr + kk);
                o += xv.x * Wreg[kk] + xv.y * Wreg[kk + 1] + xv.z * Wreg[kk + 2] + xv.w * Wreg[kk + 3];
            }
        } else {
            float2 xv = *(const float2*)(xr);
            o += xv.x * Wreg[0] + xv.y * Wreg[1];
        }
        #pragma unroll
        for (int st = DOUT; st < 64; st <<= 1) o += __shfl_xor(o, st);
        if (l < DOUT) y[(size_t)n * DOUT + c] = o;
    }
}

// ---------------- aggregation on PROJECTED rows: u = lrelu(Y[n] + sum att*Y[src] + b) ----------------
// writes Un (if WU) and normalized rows into results RSTART..3 at COL
template<int D, int COL, int RSTART, bool WU>
__global__ __launch_bounds__(256) void k_aggY(const float* __restrict__ Y,
                                              const float* __restrict__ att,
                                              const int* __restrict__ src,
                                              const int* __restrict__ offs,
                                              const float* __restrict__ bias,
                                              float* __restrict__ Un,
                                              float* __restrict__ out) {
    constexpr int E = D / 4;          // lanes per edge (float4 each)
    constexpr int S = 64 / E;         // edge slots per wave
    int tid = threadIdx.x, w = tid >> 6, l = tid & 63;
    int n = blockIdx.x * 4 + w;
    int b = offs[n], e = offs[n + 1];
    int je = l & (E - 1), slot = l / E;

    float4 a = make_float4(0.f, 0.f, 0.f, 0.f);
    int i = b + slot;
    for (; i + S < e; i += 2 * S) {
        float t0 = att[i], t1 = att[i + S];
        float4 p0 = *(const float4*)(Y + (size_t)src[i]     * D + 4 * je);
        float4 p1 = *(const float4*)(Y + (size_t)src[i + S] * D + 4 * je);
        a.x += t0 * p0.x + t1 * p1.x;
        a.y += t0 * p0.y + t1 * p1.y;
        a.z += t0 * p0.z + t1 * p1.z;
        a.w += t0 * p0.w + t1 * p1.w;
    }
    for (; i < e; i += S) {
        float t0 = att[i];
        float4 p0 = *(const float4*)(Y + (size_t)src[i] * D + 4 * je);
        a.x += t0 * p0.x; a.y += t0 * p0.y; a.z += t0 * p0.z; a.w += t0 * p0.w;
    }
    #pragma unroll
    for (int st = E; st < 64; st <<= 1) {
        a.x += __shfl_xor(a.x, st); a.y += __shfl_xor(a.y, st);
        a.z += __shfl_xor(a.z, st); a.w += __shfl_xor(a.w, st);
    }
    float4 q  = *(const float4*)(Y + (size_t)n * D + 4 * je);
    float4 bi = *(const float4*)(bias + 4 * je);
    float4 u;
    u.x = lrelu(a.x + q.x + bi.x);
    u.y = lrelu(a.y + q.y + bi.y);
    u.z = lrelu(a.z + q.z + bi.z);
    u.w = lrelu(a.w + q.w + bi.w);
    float ss = u.x * u.x + u.y * u.y + u.z * u.z + u.w * u.w;
    #pragma unroll
    for (int st = 1; st < E; st <<= 1) ss += __shfl_xor(ss, st);
    float inv = fast_rcp(fmaxf(sqrtf(ss), 1e-12f));
    if (slot < 4 - RSTART) {
        float4 nr = make_float4(u.x * inv, u.y * inv, u.z * inv, u.w * inv);
        *(float4*)(out + (size_t)(RSTART + slot) * RES + (size_t)n * OUTW + COL + 4 * je) = nr;
    }
    if (WU && slot == 4 - RSTART)
        *(float4*)(Un + (size_t)n * D + 4 * je) = u;
}

// ---------------- all B-chains in ONE dispatch, using Y shortcuts ----------------
// seg0: u1=lrelu(Y1+b1)->r0c96; u2=lrelu(u1@W2+b2)->r0c112; u3=lrelu(u2@W3+b3)->r0c128
// seg1: u2=lrelu(Y2+b2)->r1c112; u3=lrelu(u2@W3+b3)->r1c128
// seg2: u3=lrelu(Y3+b3)->r2c128
__global__ __launch_bounds__(256) void k_bchain(const float* __restrict__ Y1,
                                                const float* __restrict__ Y2,
                                                const float* __restrict__ Y3,
                                                const float* __restrict__ WLT,
                                                const float* __restrict__ b1,
                                                const float* __restrict__ b2,
                                                const float* __restrict__ b3,
                                                float* __restrict__ out) {
    __shared__ float W2s[16][17], W3s[8][17];
    __shared__ float bb1[16], bb2[16], bb3[8];
    __shared__ float mid[16][17], mid2[16][17];
    int tid = threadIdx.x;
    if (tid < 256) W2s[tid >> 4][tid & 15] = WLT[2560 + tid];
    if (tid < 128) W3s[tid >> 4][tid & 15] = WLT[2816 + tid];
    if (tid < 16) bb1[tid] = b1[tid];
    if (tid >= 32 && tid < 48) bb2[tid - 32] = b2[tid - 32];
    if (tid >= 64 && tid < 72) bb3[tid - 64] = b3[tid - 64];
    __syncthreads();

    int grp = tid >> 4, lj = tid & 15;
    int seg = blockIdx.x / 6250;
    int nb = blockIdx.x % 6250;
    int n = nb * 16 + grp;

    if (seg == 0) {
        float u1 = lrelu(Y1[(size_t)n * 16 + lj] + bb1[lj]);
        mid[grp][lj] = u1;
        float ss = u1 * u1;
        #pragma unroll
        for (int m = 8; m >= 1; m >>= 1) ss += __shfl_xor(ss, m);
        out[(size_t)n * OUTW + 96 + lj] = u1 * fast_rcp(fmaxf(sqrtf(ss), 1e-12f));
        __builtin_amdgcn_s_waitcnt(0);
        __builtin_amdgcn_sched_barrier(0);
        float o2 = bb2[lj];
        #pragma unroll
        for (int k = 0; k < 16; ++k) o2 += mid[grp][k] * W2s[lj][k];
        float u2 = lrelu(o2);
        mid2[grp][lj] = u2;
        float s2 = u2 * u2;
        #pragma unroll
        for (int m = 8; m >= 1; m >>= 1) s2 += __shfl_xor(s2, m);
        out[(size_t)n * OUTW + 112 + lj] = u2 * fast_rcp(fmaxf(sqrtf(s2), 1e-12f));
        __builtin_amdgcn_s_waitcnt(0);
        __builtin_amdgcn_sched_barrier(0);
        if (lj < 8) {
            float o3 = bb3[lj];
            #pragma unroll
            for (int k = 0; k < 16; ++k) o3 += mid2[grp][k] * W3s[lj][k];
            float u3 = lrelu(o3);
            float s3 = u3 * u3;
            #pragma unroll
            for (int m = 4; m >= 1; m >>= 1) s3 += __shfl_xor(s3, m);
            out[(size_t)n * OUTW + 128 + lj] = u3 * fast_rcp(fmaxf(sqrtf(s3), 1e-12f));
        }
    } else if (seg == 1) {
        float u2 = lrelu(Y2[(size_t)n * 16 + lj] + bb2[lj]);
        mid[grp][lj] = u2;
        float s2 = u2 * u2;
        #pragma unroll
        for (int m = 8; m >= 1; m >>= 1) s2 += __shfl_xor(s2, m);
        out[RES + (size_t)n * OUTW + 112 + lj] = u2 * fast_rcp(fmaxf(sqrtf(s2), 1e-12f));
        __builtin_amdgcn_s_waitcnt(0);
        __builtin_amdgcn_sched_barrier(0);
        if (lj < 8) {
            float o3 = bb3[lj];
            #pragma unroll
            for (int k = 0; k < 16; ++k) o3 += mid[grp][k] * W3s[lj][k];
            float u3 = lrelu(o3);
            float s3 = u3 * u3;
            #pragma unroll
            for (int m = 4; m >= 1; m >>= 1) s3 += __shfl_xor(s3, m);
            out[RES + (size_t)n * OUTW + 128 + lj] = u3 * fast_rcp(fmaxf(sqrtf(s3), 1e-12f));
        }
    } else {
        if (lj < 8) {
            float u3 = lrelu(Y3[(size_t)n * 8 + lj] + bb3[lj]);
            float s3 = u3 * u3;
            #pragma unroll
            for (int m = 4; m >= 1; m >>= 1) s3 += __shfl_xor(s3, m);
            out[2 * RES + (size_t)n * OUTW + 128 + lj] = u3 * fast_rcp(fmaxf(sqrtf(s3), 1e-12f));
        }
    }
}

// ---------------- emb block copy to all 4 results ----------------
__global__ __launch_bounds__(256) void k_emb_copy(const float* __restrict__ emb, float* __restrict__ out) {
    int idx = blockIdx.x * 256 + threadIdx.x;
    int n = idx >> 4, cc = (idx & 15) * 4;
    float4 v = *(const float4*)(emb + (size_t)n * 64 + cc);
    #pragma unroll
    for (int r = 0; r < 4; ++r)
        *(float4*)(out + (size_t)r * RES + (size_t)n * OUTW + cc) = v;
}

extern "C" void kernel_launch(void* const* d_in, const int* in_sizes, int n_in,
                              void* d_out, int out_size, void* d_ws, size_t ws_size,
                              hipStream_t stream) {
    (void)in_sizes; (void)n_in; (void)out_size;
    const float* emb = (const float*)d_in[0];
    const float* rel_embed = (const float*)d_in[1];
    const float* W_R = (const float*)d_in[2];
    const float* W0 = (const float*)d_in[3];  const float* b0 = (const float*)d_in[4];
    const float* W1 = (const float*)d_in[5];  const float* b1 = (const float*)d_in[6];
    const float* W2 = (const float*)d_in[7];  const float* b2 = (const float*)d_in[8];
    const float* W3 = (const float*)d_in[9];  const float* b3 = (const float*)d_in[10];
    const int* src = (const int*)d_in[11];
    const int* dst = (const int*)d_in[12];
    const int* etype = (const int*)d_in[13];
    float* out = (float*)d_out;

    char* p = (char*)d_ws;
    auto alloc = [&](size_t bytes) { char* q = p; p += (bytes + 255) & ~(size_t)255; return q; };
    int* offs  = (int*)alloc((size_t)(N_NODES + 1) * 4);
    float* att = (float*)alloc((size_t)N_EDGES * 4);
    int* eperm = (int*)alloc((size_t)N_EDGES * 4);
    int* srcp  = (int*)alloc((size_t)N_EDGES * 4);
    int* dstp  = (int*)alloc((size_t)N_EDGES * 4);
    int* cnt   = (int*)alloc(64);
    int* roff  = (int*)alloc(68);
    int* cur   = (int*)alloc(64);
    unsigned short* embB = (unsigned short*)alloc((size_t)N_NODES * 64 * 2);
    unsigned short* WT   = (unsigned short*)alloc((size_t)65536 * 2);
    float* WLT = (float*)alloc((size_t)2944 * 4);
    float* U1  = (float*)alloc((size_t)N_NODES * 32 * 4);
    float* U2  = (float*)alloc((size_t)N_NODES * 16 * 4);
    float* U3  = (float*)alloc((size_t)N_NODES * 16 * 4);
    float* Y0  = (float*)alloc((size_t)N_NODES * 32 * 4);
    float* Y1  = (float*)alloc((size_t)N_NODES * 16 * 4);
    float* Y2  = (float*)alloc((size_t)N_NODES * 16 * 4);
    float* Y3  = (float*)alloc((size_t)N_NODES * 8 * 4);
    size_t fixed = (size_t)(p - (char*)d_ws);
    size_t per_rel = (size_t)N_NODES * 64 * 2;   // bf16 buf per relation
    int chunk = 1;
    if (ws_size > fixed + per_rel)
        chunk = (int)((ws_size - fixed) / per_rel);
    if (chunk > 4) chunk = 4;                    // keep footprint L2/L3-resident
    if (chunk < 1) chunk = 1;
    unsigned short* allbuf = (unsigned short*)p;

    // prep
    k_offsets<<<(N_NODES + 256) / 256, 256, 0, stream>>>(dst, offs);
    k_zero<<<1, 64, 0, stream>>>(cnt);
    k_hist<<<N_EDGES / 256, 256, 0, stream>>>(etype, cnt);
    k_scan<<<1, 64, 0, stream>>>(cnt, roff, cur);
    k_scatter<<<N_EDGES / 256, 256, 0, stream>>>(etype, src, dst, cur, eperm, srcp, dstp);
    k_cast_emb<<<N_NODES * 16 / 256, 256, 0, stream>>>(emb, embB);
    k_prep_wr<<<256, 256, 0, stream>>>(W_R, WT);
    k_prep_wl<<<12, 256, 0, stream>>>(W0, W1, W2, W3, WLT);

    // attention: chunked MFMA transform + edge scores (bufs stay cache-resident)
    for (int c0 = 0; c0 < N_RELS; c0 += chunk) {
        int nc = N_RELS - c0 < chunk ? N_RELS - c0 : chunk;
        k_gemm_mfma<<<(N_NODES + 127) / 128, 256, 0, stream>>>(embB, WT + (size_t)c0 * 4096, allbuf, nc);
        k_edge_att4<<<2048, 256, 0, stream>>>(allbuf, rel_embed, srcp, dstp, eperm, roff, c0, nc, att);
    }
    k_softmax<<<N_NODES / 32, 256, 0, stream>>>(att, offs);

    // A-chain: dense-project-then-aggregate (linearity: (x+Nh)@W = Y[n] + sum att*Y[src])
    k_dense<64, 32><<<3125, 256, 0, stream>>>(emb, WLT,        Y0);
    k_aggY<32, 64, 0, true ><<<N_NODES / 4, 256, 0, stream>>>(Y0, att, src, offs, b0, U1, out);
    k_dense<32, 16><<<3125, 256, 0, stream>>>(U1,  WLT + 2048, Y1);
    k_aggY<16, 96, 1, true ><<<N_NODES / 4, 256, 0, stream>>>(Y1, att, src, offs, b1, U2, out);
    k_dense<16, 16><<<3125, 256, 0, stream>>>(U2,  WLT + 2560, Y2);
    k_aggY<16, 112, 2, true><<<N_NODES / 4, 256, 0, stream>>>(Y2, att, src, offs, b2, U3, out);
    k_dense<16, 8><<<3125, 256, 0, stream>>>(U3,  WLT + 2816, Y3);
    k_aggY<8, 128, 3, false><<<N_NODES / 4, 256, 0, stream>>>(Y3, att, src, offs, b3, nullptr, out);

    // all B-chains, one dispatch (first hop of each uses Y shortcut)
    k_bchain<<<18750, 256, 0, stream>>>(Y1, Y2, Y3, WLT, b1, b2, b3, out);

    // emb block
    k_emb_copy<<<N_NODES * 16 / 256, 256, 0, stream>>>(emb, out);
}

// Round 8
// 628.336 us; speedup vs baseline: 1.1566x; 1.0324x over previous
//
#include <hip/hip_runtime.h>
#include <hip/hip_bf16.h>
#include <math.h>

#define N_NODES 100000
#define N_RELS 16
#define N_EDGES 1600000
#define OUTW 136   // 64+32+16+16+8
#define NEG_SLOPE 0.01f
#define RES ((size_t)N_NODES * OUTW)

typedef __attribute__((ext_vector_type(8))) short short8;           // 8 bf16 (4 VGPR)
typedef __attribute__((ext_vector_type(8))) unsigned short ushort8;
typedef __attribute__((ext_vector_type(4))) float f32x4;

__device__ __forceinline__ float lrelu(float x) { return x >= 0.f ? x : NEG_SLOPE * x; }
__device__ __forceinline__ float fast_rcp(float x) { return __builtin_amdgcn_rcpf(x); }
__device__ __forceinline__ float fast_tanh(float x) {
    float e = __expf(2.f * x);
    return 1.f - 2.f * fast_rcp(e + 1.f);
}
__device__ __forceinline__ float bf1(unsigned short u) { union { unsigned u; float f; } v; v.u = ((unsigned)u) << 16; return v.f; }
__device__ __forceinline__ unsigned short f2bf(float f) {
    union { float f; unsigned u; } v; v.f = f;
    unsigned x = v.u + 0x7FFF + ((v.u >> 16) & 1);
    return (unsigned short)(x >> 16);
}

// ---------------- fused prep: cast emb, transpose W_R, transpose layer W, CSR offsets, zero cnt ----------------
__global__ __launch_bounds__(256) void k_prep(const float* __restrict__ emb, unsigned short* __restrict__ embB,
                                              const float* __restrict__ WR, unsigned short* __restrict__ WT,
                                              const float* __restrict__ W0, const float* __restrict__ W1,
                                              const float* __restrict__ W2, const float* __restrict__ W3,
                                              float* __restrict__ WLT,
                                              const int* __restrict__ dst, int* __restrict__ offs,
                                              int* __restrict__ cnt) {
    int blk = blockIdx.x, tid = threadIdx.x;
    if (blk < 6250) {                       // cast emb: 1.6M float4 slots
        int id = blk * 256 + tid;
        float4 v = *(const float4*)(emb + (size_t)id * 4);
        ushort4 o; o.x = f2bf(v.x); o.y = f2bf(v.y); o.z = f2bf(v.z); o.w = f2bf(v.w);
        *(ushort4*)(embB + (size_t)id * 4) = o;
    } else if (blk < 6506) {                // W_R[r][k][n] -> WT[r][n][k] bf16
        int id = (blk - 6250) * 256 + tid;
        int r = id >> 12, rem = id & 4095, n = rem >> 6, k = rem & 63;
        WT[id] = f2bf(WR[(r << 12) + (k << 6) + n]);
    } else if (blk < 6518) {                // layer weights transposed [c][k] fp32
        int id = (blk - 6506) * 256 + tid;
        if (id < 2944) {
            float v;
            if (id < 2048)      { int c = id >> 6, k = id & 63;                  v = W0[k * 32 + c]; }
            else if (id < 2560) { int r = id - 2048; int c = r >> 5, k = r & 31; v = W1[k * 16 + c]; }
            else if (id < 2816) { int r = id - 2560; int c = r >> 4, k = r & 15; v = W2[k * 16 + c]; }
            else                { int r = id - 2816; int c = r >> 4, k = r & 15; v = W3[k * 8 + c]; }
            WLT[id] = v;
        }
    } else if (blk < 6909) {                // CSR offsets (binary search over sorted dst)
        int n = (blk - 6518) * 256 + tid;
        if (n <= N_NODES) {
            int lo = 0, hi = N_EDGES;
            while (lo < hi) { int mid = (lo + hi) >> 1; if (dst[mid] < n) lo = mid + 1; else hi = mid; }
            offs[n] = lo;
        }
    } else {                                // zero relation counters
        if (tid < 16) cnt[tid] = 0;
    }
}

// ---------------- etype histogram / scan / scatter ----------------
__global__ __launch_bounds__(256) void k_hist(const int* __restrict__ etype, int* __restrict__ cnt) {
    __shared__ int lcnt[16];
    int tid = threadIdx.x;
    if (tid < 16) lcnt[tid] = 0;
    __syncthreads();
    atomicAdd(&lcnt[etype[blockIdx.x * 256 + tid]], 1);
    __syncthreads();
    if (tid < 16 && lcnt[tid]) atomicAdd(&cnt[tid], lcnt[tid]);
}

__global__ void k_scan(const int* __restrict__ cnt, int* __restrict__ roff, int* __restrict__ cur) {
    if (threadIdx.x == 0) {
        int a = 0;
        for (int r = 0; r < 16; ++r) { roff[r] = a; cur[r] = a; a += cnt[r]; }
        roff[16] = a;
    }
}

__global__ __launch_bounds__(256) void k_scatter(const int* __restrict__ etype,
                                                 const int* __restrict__ src,
                                                 const int* __restrict__ dst,
                                                 int* __restrict__ cur, int* __restrict__ eperm,
                                                 int* __restrict__ srcp, int* __restrict__ dstp) {
    __shared__ int lcnt[16], lbase[16], loff[16];
    int tid = threadIdx.x;
    if (tid < 16) { lcnt[tid] = 0; loff[tid] = 0; }
    __syncthreads();
    int e = blockIdx.x * 256 + tid;
    int t = etype[e];
    atomicAdd(&lcnt[t], 1);
    __syncthreads();
    if (tid < 16) lbase[tid] = lcnt[tid] ? atomicAdd(&cur[tid], lcnt[tid]) : 0;
    __syncthreads();
    int rank = atomicAdd(&loff[t], 1);
    int pos = lbase[t] + rank;
    eperm[pos] = e;
    srcp[pos] = src[e];
    dstp[pos] = dst[e];
}

// ---------------- MFMA GEMM: bufs[cr] = embB @ W_R[c0+cr]  (bf16 in/out) ----------------
__global__ __launch_bounds__(256) void k_gemm_mfma(const unsigned short* __restrict__ embB,
                                                   const unsigned short* __restrict__ WT,   // pre-offset by c0
                                                   unsigned short* __restrict__ bufs, int nrel) {
    int tid = threadIdx.x, w = tid >> 6, l = tid & 63;
    int row0 = blockIdx.x * 128 + w * 32;
    int rlo = l & 15, rhi = l >> 4;

    short8 a[2][2];
    #pragma unroll
    for (int rb = 0; rb < 2; ++rb)
        #pragma unroll
        for (int ks = 0; ks < 2; ++ks) {
            int r = row0 + rb * 16 + rlo;
            if (r >= N_NODES) r = N_NODES - 1;
            a[rb][ks] = *(const short8*)(embB + (size_t)r * 64 + ks * 32 + rhi * 8);
        }

    for (int cr = 0; cr < nrel; ++cr) {
        const unsigned short* wt = WT + ((size_t)cr << 12);
        f32x4 acc[2][4];
        #pragma unroll
        for (int rb = 0; rb < 2; ++rb)
            #pragma unroll
            for (int cb = 0; cb < 4; ++cb) acc[rb][cb] = (f32x4){0.f, 0.f, 0.f, 0.f};
        #pragma unroll
        for (int cb = 0; cb < 4; ++cb) {
            short8 b0 = *(const short8*)(wt + (cb * 16 + rlo) * 64 + rhi * 8);
            short8 b1 = *(const short8*)(wt + (cb * 16 + rlo) * 64 + 32 + rhi * 8);
            acc[0][cb] = __builtin_amdgcn_mfma_f32_16x16x32_bf16(a[0][0], b0, acc[0][cb], 0, 0, 0);
            acc[0][cb] = __builtin_amdgcn_mfma_f32_16x16x32_bf16(a[0][1], b1, acc[0][cb], 0, 0, 0);
            acc[1][cb] = __builtin_amdgcn_mfma_f32_16x16x32_bf16(a[1][0], b0, acc[1][cb], 0, 0, 0);
            acc[1][cb] = __builtin_amdgcn_mfma_f32_16x16x32_bf16(a[1][1], b1, acc[1][cb], 0, 0, 0);
        }
        unsigned short* ob = bufs + (size_t)cr * N_NODES * 64;
        #pragma unroll
        for (int rb = 0; rb < 2; ++rb)
            #pragma unroll
            for (int cb = 0; cb < 4; ++cb)
                #pragma unroll
                for (int i = 0; i < 4; ++i) {
                    int gr = row0 + rb * 16 + rhi * 4 + i;
                    if (gr < N_NODES) ob[(size_t)gr * 64 + cb * 16 + rlo] = f2bf(acc[rb][cb][i]);
                }
    }
}

// ---------------- attention over chunk [c0, c0+nc): 8 lanes/edge, 8 edges/wave ----------------
__global__ __launch_bounds__(256) void k_edge_att4(const unsigned short* __restrict__ bufs,
                                                   const float* __restrict__ rel,
                                                   const int* __restrict__ srcp,
                                                   const int* __restrict__ dstp,
                                                   const int* __restrict__ eperm,
                                                   const int* __restrict__ roff,
                                                   int c0, int nc, float* __restrict__ att) {
    int lo = roff[c0];
    int cnt = roff[c0 + nc] - lo;
    int bnd0 = (nc > 1) ? roff[c0 + 1] - lo : 0x7fffffff;
    int bnd1 = (nc > 2) ? roff[c0 + 2] - lo : 0x7fffffff;
    int bnd2 = (nc > 3) ? roff[c0 + 3] - lo : 0x7fffffff;
    int tid = threadIdx.x, lane = tid & 63;
    int sub = lane >> 3, lj = lane & 7, d0 = lj * 8;
    int gw = (blockIdx.x * 256 + tid) >> 6;
    int nw = (gridDim.x * 256) >> 6;
    for (int i = gw * 8 + sub; i < cnt; i += nw * 8) {
        int t = (i >= bnd0) + (i >= bnd1) + (i >= bnd2);
        const unsigned short* bb = bufs + (size_t)t * N_NODES * 64;
        const float* rr = rel + (size_t)(c0 + t) * 64 + d0;
        size_t s = (size_t)srcp[lo + i], dn = (size_t)dstp[lo + i];
        ushort8 tv = *(const ushort8*)(bb + s * 64 + d0);
        ushort8 hv = *(const ushort8*)(bb + dn * 64 + d0);
        float4 r0 = *(const float4*)(rr);
        float4 r1 = *(const float4*)(rr + 4);
        float v = bf1(tv[0]) * fast_tanh(bf1(hv[0]) + r0.x)
                + bf1(tv[1]) * fast_tanh(bf1(hv[1]) + r0.y)
                + bf1(tv[2]) * fast_tanh(bf1(hv[2]) + r0.z)
                + bf1(tv[3]) * fast_tanh(bf1(hv[3]) + r0.w)
                + bf1(tv[4]) * fast_tanh(bf1(hv[4]) + r1.x)
                + bf1(tv[5]) * fast_tanh(bf1(hv[5]) + r1.y)
                + bf1(tv[6]) * fast_tanh(bf1(hv[6]) + r1.z)
                + bf1(tv[7]) * fast_tanh(bf1(hv[7]) + r1.w);
        #pragma unroll
        for (int m = 1; m < 8; m <<= 1) v += __shfl_xor(v, m);
        if (lj == 0) att[eperm[lo + i]] = v;
    }
}

// ---------------- per-dst softmax, 8 lanes per node ----------------
__global__ __launch_bounds__(256) void k_softmax(float* __restrict__ att, const int* __restrict__ offs) {
    int tid = threadIdx.x;
    int n = blockIdx.x * 32 + (tid >> 3);
    int j = tid & 7;
    int b = offs[n], e = offs[n + 1];
    if (b >= e) return;
    float m = -INFINITY;
    for (int i = b + j; i < e; i += 8) m = fmaxf(m, att[i]);
    #pragma unroll
    for (int s = 4; s >= 1; s >>= 1) m = fmaxf(m, __shfl_xor(m, s));
    float sum = 0.f;
    for (int i = b + j; i < e; i += 8) { float v = __expf(att[i] - m); att[i] = v; sum += v; }
    #pragma unroll
    for (int s = 4; s >= 1; s >>= 1) sum += __shfl_xor(sum, s);
    float inv = fast_rcp(sum);
    for (int i = b + j; i < e; i += 8) att[i] *= inv;
}

// ---------------- dense0: Y0 = emb @ W0 AND copy emb block to all 4 results ----------------
__global__ __launch_bounds__(256) void k_dense0(const float* __restrict__ emb,
                                                const float* __restrict__ WLT,   // W0T [32][64]
                                                float* __restrict__ Y0,
                                                float* __restrict__ out) {
    int tid = threadIdx.x, w = tid >> 6, l = tid & 63;
    int c = l & 31, g = l >> 5;
    float Wreg[32];
    #pragma unroll
    for (int kk = 0; kk < 32; ++kk) Wreg[kk] = WLT[(size_t)c * 64 + g * 32 + kk];
    int nw = gridDim.x * 4;
    for (int n = blockIdx.x * 4 + w; n < N_NODES; n += nw) {
        const float* xr = emb + (size_t)n * 64;
        float v = xr[l];
        #pragma unroll
        for (int r = 0; r < 4; ++r)
            out[(size_t)r * RES + (size_t)n * OUTW + l] = v;
        float o = 0.f;
        #pragma unroll
        for (int kk = 0; kk < 32; kk += 4) {
            float4 xv = *(const float4*)(xr + g * 32 + kk);
            o += xv.x * Wreg[kk] + xv.y * Wreg[kk + 1] + xv.z * Wreg[kk + 2] + xv.w * Wreg[kk + 3];
        }
        o += __shfl_xor(o, 32);
        if (l < 32) Y0[(size_t)n * 32 + c] = o;
    }
}

// ---------------- fused layer: u = lrelu(Y[n] + sum att*Y[src] + b); norm->out; Ynext = u @ Wnext ----------------
template<int D, int DN, int COL, int RSTART, bool PROJ>
__global__ __launch_bounds__(256) void k_aggF(const float* __restrict__ Y,
                                              const float* __restrict__ att,
                                              const int* __restrict__ src,
                                              const int* __restrict__ offs,
                                              const float* __restrict__ bias,
                                              const float* __restrict__ WTn,   // next-layer [c][k] fp32
                                              float* __restrict__ Yn,
                                              float* __restrict__ out) {
    constexpr int E = D / 4;              // lanes per edge (float4 each)
    constexpr int S = 64 / E;             // edge slots per wave
    constexpr int G = PROJ ? (64 / DN) : 1;
    constexpr int KS = PROJ ? (D / G) : 1;
    __shared__ float xm[4][PROJ ? D : 4];
    int tid = threadIdx.x, w = tid >> 6, l = tid & 63;
    int n = blockIdx.x * 4 + w;
    int b = offs[n], e = offs[n + 1];
    int je = l & (E - 1), slot = l / E;

    float Wreg[KS];
    if constexpr (PROJ) {
        int c = l & (DN - 1), g = l / DN;
        #pragma unroll
        for (int kk = 0; kk < KS; ++kk) Wreg[kk] = WTn[(size_t)c * D + g * KS + kk];
    }

    float4 a = make_float4(0.f, 0.f, 0.f, 0.f);
    int i = b + slot;
    for (; i + S < e; i += 2 * S) {
        float t0 = att[i], t1 = att[i + S];
        float4 p0 = *(const float4*)(Y + (size_t)src[i]     * D + 4 * je);
        float4 p1 = *(const float4*)(Y + (size_t)src[i + S] * D + 4 * je);
        a.x += t0 * p0.x + t1 * p1.x;
        a.y += t0 * p0.y + t1 * p1.y;
        a.z += t0 * p0.z + t1 * p1.z;
        a.w += t0 * p0.w + t1 * p1.w;
    }
    for (; i < e; i += S) {
        float t0 = att[i];
        float4 p0 = *(const float4*)(Y + (size_t)src[i] * D + 4 * je);
        a.x += t0 * p0.x; a.y += t0 * p0.y; a.z += t0 * p0.z; a.w += t0 * p0.w;
    }
    #pragma unroll
    for (int st = E; st < 64; st <<= 1) {
        a.x += __shfl_xor(a.x, st); a.y += __shfl_xor(a.y, st);
        a.z += __shfl_xor(a.z, st); a.w += __shfl_xor(a.w, st);
    }
    float4 q  = *(const float4*)(Y + (size_t)n * D + 4 * je);
    float4 bi = *(const float4*)(bias + 4 * je);
    float4 u;
    u.x = lrelu(a.x + q.x + bi.x);
    u.y = lrelu(a.y + q.y + bi.y);
    u.z = lrelu(a.z + q.z + bi.z);
    u.w = lrelu(a.w + q.w + bi.w);
    float ss = u.x * u.x + u.y * u.y + u.z * u.z + u.w * u.w;
    #pragma unroll
    for (int st = 1; st < E; st <<= 1) ss += __shfl_xor(ss, st);
    float inv = fast_rcp(fmaxf(sqrtf(ss), 1e-12f));
    if (slot < 4 - RSTART) {
        float4 nr = make_float4(u.x * inv, u.y * inv, u.z * inv, u.w * inv);
        *(float4*)(out + (size_t)(RSTART + slot) * RES + (size_t)n * OUTW + COL + 4 * je) = nr;
    }
    if constexpr (PROJ) {
        if (slot == S - 1) *(float4*)&xm[w][4 * je] = u;
        __builtin_amdgcn_s_waitcnt(0);
        __builtin_amdgcn_sched_barrier(0);
        int c = l & (DN - 1), g = l / DN;
        float o = 0.f;
        if constexpr (KS >= 4) {
            #pragma unroll
            for (int kk = 0; kk < KS; kk += 4) {
                float4 xv = *(const float4*)&xm[w][g * KS + kk];
                o += xv.x * Wreg[kk] + xv.y * Wreg[kk + 1] + xv.z * Wreg[kk + 2] + xv.w * Wreg[kk + 3];
            }
        } else {
            float2 xv = *(const float2*)&xm[w][g * KS];
            o += xv.x * Wreg[0] + xv.y * Wreg[1];
        }
        #pragma unroll
        for (int st = DN; st < 64; st <<= 1) o += __shfl_xor(o, st);
        if (l < DN) Yn[(size_t)n * DN + c] = o;
    }
}

// ---------------- all B-chains in ONE dispatch, using Y shortcuts ----------------
__global__ __launch_bounds__(256) void k_bchain(const float* __restrict__ Y1,
                                                const float* __restrict__ Y2,
                                                const float* __restrict__ Y3,
                                                const float* __restrict__ WLT,
                                                const float* __restrict__ b1,
                                                const float* __restrict__ b2,
                                                const float* __restrict__ b3,
                                                float* __restrict__ out) {
    __shared__ float W2s[16][17], W3s[8][17];
    __shared__ float bb1[16], bb2[16], bb3[8];
    __shared__ float mid[16][17], mid2[16][17];
    int tid = threadIdx.x;
    if (tid < 256) W2s[tid >> 4][tid & 15] = WLT[2560 + tid];
    if (tid < 128) W3s[tid >> 4][tid & 15] = WLT[2816 + tid];
    if (tid < 16) bb1[tid] = b1[tid];
    if (tid >= 32 && tid < 48) bb2[tid - 32] = b2[tid - 32];
    if (tid >= 64 && tid < 72) bb3[tid - 64] = b3[tid - 64];
    __syncthreads();

    int grp = tid >> 4, lj = tid & 15;
    int seg = blockIdx.x / 6250;
    int nb = blockIdx.x % 6250;
    int n = nb * 16 + grp;

    if (seg == 0) {
        float u1 = lrelu(Y1[(size_t)n * 16 + lj] + bb1[lj]);
        mid[grp][lj] = u1;
        float ss = u1 * u1;
        #pragma unroll
        for (int m = 8; m >= 1; m >>= 1) ss += __shfl_xor(ss, m);
        out[(size_t)n * OUTW + 96 + lj] = u1 * fast_rcp(fmaxf(sqrtf(ss), 1e-12f));
        __builtin_amdgcn_s_waitcnt(0);
        __builtin_amdgcn_sched_barrier(0);
        float o2 = bb2[lj];
        #pragma unroll
        for (int k = 0; k < 16; ++k) o2 += mid[grp][k] * W2s[lj][k];
        float u2 = lrelu(o2);
        mid2[grp][lj] = u2;
        float s2 = u2 * u2;
        #pragma unroll
        for (int m = 8; m >= 1; m >>= 1) s2 += __shfl_xor(s2, m);
        out[(size_t)n * OUTW + 112 + lj] = u2 * fast_rcp(fmaxf(sqrtf(s2), 1e-12f));
        __builtin_amdgcn_s_waitcnt(0);
        __builtin_amdgcn_sched_barrier(0);
        if (lj < 8) {
            float o3 = bb3[lj];
            #pragma unroll
            for (int k = 0; k < 16; ++k) o3 += mid2[grp][k] * W3s[lj][k];
            float u3 = lrelu(o3);
            float s3 = u3 * u3;
            #pragma unroll
            for (int m = 4; m >= 1; m >>= 1) s3 += __shfl_xor(s3, m);
            out[(size_t)n * OUTW + 128 + lj] = u3 * fast_rcp(fmaxf(sqrtf(s3), 1e-12f));
        }
    } else if (seg == 1) {
        float u2 = lrelu(Y2[(size_t)n * 16 + lj] + bb2[lj]);
        mid[grp][lj] = u2;
        float s2 = u2 * u2;
        #pragma unroll
        for (int m = 8; m >= 1; m >>= 1) s2 += __shfl_xor(s2, m);
        out[RES + (size_t)n * OUTW + 112 + lj] = u2 * fast_rcp(fmaxf(sqrtf(s2), 1e-12f));
        __builtin_amdgcn_s_waitcnt(0);
        __builtin_amdgcn_sched_barrier(0);
        if (lj < 8) {
            float o3 = bb3[lj];
            #pragma unroll
            for (int k = 0; k < 16; ++k) o3 += mid[grp][k] * W3s[lj][k];
            float u3 = lrelu(o3);
            float s3 = u3 * u3;
            #pragma unroll
            for (int m = 4; m >= 1; m >>= 1) s3 += __shfl_xor(s3, m);
            out[RES + (size_t)n * OUTW + 128 + lj] = u3 * fast_rcp(fmaxf(sqrtf(s3), 1e-12f));
        }
    } else {
        if (lj < 8) {
            float u3 = lrelu(Y3[(size_t)n * 8 + lj] + bb3[lj]);
            float s3 = u3 * u3;
            #pragma unroll
            for (int m = 4; m >= 1; m >>= 1) s3 += __shfl_xor(s3, m);
            out[2 * RES + (size_t)n * OUTW + 128 + lj] = u3 * fast_rcp(fmaxf(sqrtf(s3), 1e-12f));
        }
    }
}

extern "C" void kernel_launch(void* const* d_in, const int* in_sizes, int n_in,
                              void* d_out, int out_size, void* d_ws, size_t ws_size,
                              hipStream_t stream) {
    (void)in_sizes; (void)n_in; (void)out_size;
    const float* emb = (const float*)d_in[0];
    const float* rel_embed = (const float*)d_in[1];
    const float* W_R = (const float*)d_in[2];
    const float* W0 = (const float*)d_in[3];  const float* b0 = (const float*)d_in[4];
    const float* W1 = (const float*)d_in[5];  const float* b1 = (const float*)d_in[6];
    const float* W2 = (const float*)d_in[7];  const float* b2 = (const float*)d_in[8];
    const float* W3 = (const float*)d_in[9];  const float* b3 = (const float*)d_in[10];
    const int* src = (const int*)d_in[11];
    const int* dst = (const int*)d_in[12];
    const int* etype = (const int*)d_in[13];
    float* out = (float*)d_out;

    char* p = (char*)d_ws;
    auto alloc = [&](size_t bytes) { char* q = p; p += (bytes + 255) & ~(size_t)255; return q; };
    int* offs  = (int*)alloc((size_t)(N_NODES + 1) * 4);
    float* att = (float*)alloc((size_t)N_EDGES * 4);
    int* eperm = (int*)alloc((size_t)N_EDGES * 4);
    int* srcp  = (int*)alloc((size_t)N_EDGES * 4);
    int* dstp  = (int*)alloc((size_t)N_EDGES * 4);
    int* cnt   = (int*)alloc(64);
    int* roff  = (int*)alloc(68);
    int* cur   = (int*)alloc(64);
    unsigned short* embB = (unsigned short*)alloc((size_t)N_NODES * 64 * 2);
    unsigned short* WT   = (unsigned short*)alloc((size_t)65536 * 2);
    float* WLT = (float*)alloc((size_t)2944 * 4);
    float* Y0  = (float*)alloc((size_t)N_NODES * 32 * 4);
    float* Y1  = (float*)alloc((size_t)N_NODES * 16 * 4);
    float* Y2  = (float*)alloc((size_t)N_NODES * 16 * 4);
    float* Y3  = (float*)alloc((size_t)N_NODES * 8 * 4);
    size_t fixed = (size_t)(p - (char*)d_ws);
    size_t per_rel = (size_t)N_NODES * 64 * 2;   // bf16 buf per relation
    int chunk = 1;
    if (ws_size > fixed + per_rel)
        chunk = (int)((ws_size - fixed) / per_rel);
    if (chunk > 4) chunk = 4;                    // keep footprint L2/L3-resident
    if (chunk < 1) chunk = 1;
    unsigned short* allbuf = (unsigned short*)p;

    // fused prep (cast emb, W_R^T, W^T, CSR offsets, zero cnt)
    k_prep<<<6910, 256, 0, stream>>>(emb, embB, W_R, WT, W0, W1, W2, W3, WLT, dst, offs, cnt);
    k_hist<<<N_EDGES / 256, 256, 0, stream>>>(etype, cnt);
    k_scan<<<1, 64, 0, stream>>>(cnt, roff, cur);
    k_scatter<<<N_EDGES / 256, 256, 0, stream>>>(etype, src, dst, cur, eperm, srcp, dstp);

    // attention: chunked MFMA transform + edge scores (bufs stay cache-resident)
    for (int c0 = 0; c0 < N_RELS; c0 += chunk) {
        int nc = N_RELS - c0 < chunk ? N_RELS - c0 : chunk;
        k_gemm_mfma<<<(N_NODES + 127) / 128, 256, 0, stream>>>(embB, WT + (size_t)c0 * 4096, allbuf, nc);
        k_edge_att4<<<2048, 256, 0, stream>>>(allbuf, rel_embed, srcp, dstp, eperm, roff, c0, nc, att);
    }
    k_softmax<<<N_NODES / 32, 256, 0, stream>>>(att, offs);

    // Y0 = emb @ W0 (+ emb block copy into all 4 results)
    k_dense0<<<3125, 256, 0, stream>>>(emb, WLT, Y0, out);

    // A-chain: fused aggregate + bias/lrelu + norm-broadcast + next-layer projection
    k_aggF<32, 16,  64, 0, true ><<<N_NODES / 4, 256, 0, stream>>>(Y0, att, src, offs, b0, WLT + 2048, Y1, out);
    k_aggF<16, 16,  96, 1, true ><<<N_NODES / 4, 256, 0, stream>>>(Y1, att, src, offs, b1, WLT + 2560, Y2, out);
    k_aggF<16,  8, 112, 2, true ><<<N_NODES / 4, 256, 0, stream>>>(Y2, att, src, offs, b2, WLT + 2816, Y3, out);
    k_aggF< 8,  8, 128, 3, false><<<N_NODES / 4, 256, 0, stream>>>(Y3, att, src, offs, b3, nullptr, nullptr, out);

    // all B-chains, one dispatch (first hop of each uses Y shortcut)
    k_bchain<<<18750, 256, 0, stream>>>(Y1, Y2, Y3, WLT, b1, b2, b3, out);
}

// Round 9
// 554.520 us; speedup vs baseline: 1.3105x; 1.1331x over previous
//
#include <hip/hip_runtime.h>
#include <hip/hip_bf16.h>
#include <math.h>

#define N_NODES 100000
#define N_RELS 16
#define N_EDGES 1600000
#define OUTW 136   // 64+32+16+16+8
#define NEG_SLOPE 0.01f
#define RES ((size_t)N_NODES * OUTW)

typedef __attribute__((ext_vector_type(8))) short short8;           // 8 bf16 (4 VGPR)
typedef __attribute__((ext_vector_type(4))) float f32x4;

__device__ __forceinline__ float lrelu(float x) { return x >= 0.f ? x : NEG_SLOPE * x; }
__device__ __forceinline__ float fast_rcp(float x) { return __builtin_amdgcn_rcpf(x); }
__device__ __forceinline__ float fast_tanh(float x) {
    float e = __expf(2.f * x);
    return 1.f - 2.f * fast_rcp(e + 1.f);
}
__device__ __forceinline__ unsigned short f2bf(float f) {
    union { float f; unsigned u; } v; v.f = f;
    unsigned x = v.u + 0x7FFF + ((v.u >> 16) & 1);
    return (unsigned short)(x >> 16);
}

// ---------------- fused prep: cast emb, transpose W_R, transpose layer W, CSR offsets, zero cnt ----------------
__global__ __launch_bounds__(256) void k_prep(const float* __restrict__ emb, unsigned short* __restrict__ embB,
                                              const float* __restrict__ WR, unsigned short* __restrict__ WT,
                                              const float* __restrict__ W0, const float* __restrict__ W1,
                                              const float* __restrict__ W2, const float* __restrict__ W3,
                                              float* __restrict__ WLT,
                                              const int* __restrict__ dst, int* __restrict__ offs,
                                              int* __restrict__ cnt) {
    int blk = blockIdx.x, tid = threadIdx.x;
    if (blk < 6250) {                       // cast emb: 1.6M float4 slots
        int id = blk * 256 + tid;
        float4 v = *(const float4*)(emb + (size_t)id * 4);
        ushort4 o; o.x = f2bf(v.x); o.y = f2bf(v.y); o.z = f2bf(v.z); o.w = f2bf(v.w);
        *(ushort4*)(embB + (size_t)id * 4) = o;
    } else if (blk < 6506) {                // W_R[r][k][n] -> WT[r][n][k] bf16
        int id = (blk - 6250) * 256 + tid;
        int r = id >> 12, rem = id & 4095, n = rem >> 6, k = rem & 63;
        WT[id] = f2bf(WR[(r << 12) + (k << 6) + n]);
    } else if (blk < 6518) {                // layer weights transposed [c][k] fp32
        int id = (blk - 6506) * 256 + tid;
        if (id < 2944) {
            float v;
            if (id < 2048)      { int c = id >> 6, k = id & 63;                  v = W0[k * 32 + c]; }
            else if (id < 2560) { int r = id - 2048; int c = r >> 5, k = r & 31; v = W1[k * 16 + c]; }
            else if (id < 2816) { int r = id - 2560; int c = r >> 4, k = r & 15; v = W2[k * 16 + c]; }
            else                { int r = id - 2816; int c = r >> 4, k = r & 15; v = W3[k * 8 + c]; }
            WLT[id] = v;
        }
    } else if (blk < 6909) {                // CSR offsets (binary search over sorted dst)
        int n = (blk - 6518) * 256 + tid;
        if (n <= N_NODES) {
            int lo = 0, hi = N_EDGES;
            while (lo < hi) { int mid = (lo + hi) >> 1; if (dst[mid] < n) lo = mid + 1; else hi = mid; }
            offs[n] = lo;
        }
    } else {                                // zero relation counters
        if (tid < 16) cnt[tid] = 0;
    }
}

// ---------------- etype histogram / scan / scatter ----------------
__global__ __launch_bounds__(256) void k_hist(const int* __restrict__ etype, int* __restrict__ cnt) {
    __shared__ int lcnt[16];
    int tid = threadIdx.x;
    if (tid < 16) lcnt[tid] = 0;
    __syncthreads();
    atomicAdd(&lcnt[etype[blockIdx.x * 256 + tid]], 1);
    __syncthreads();
    if (tid < 16 && lcnt[tid]) atomicAdd(&cnt[tid], lcnt[tid]);
}

__global__ void k_scan(const int* __restrict__ cnt, int* __restrict__ roff, int* __restrict__ cur,
                       int* __restrict__ bo) {
    if (threadIdx.x == 0) {
        int a = 0, nb = 0;
        for (int r = 0; r < 16; ++r) {
            roff[r] = a; cur[r] = a; bo[r] = nb;
            a += cnt[r]; nb += (cnt[r] + 15) >> 4;
        }
        roff[16] = a; bo[16] = nb;
    }
}

__global__ __launch_bounds__(256) void k_scatter(const int* __restrict__ etype,
                                                 const int* __restrict__ src,
                                                 const int* __restrict__ dst,
                                                 int* __restrict__ cur, int* __restrict__ eperm,
                                                 int* __restrict__ srcp, int* __restrict__ dstp) {
    __shared__ int lcnt[16], lbase[16], loff[16];
    int tid = threadIdx.x;
    if (tid < 16) { lcnt[tid] = 0; loff[tid] = 0; }
    __syncthreads();
    int e = blockIdx.x * 256 + tid;
    int t = etype[e];
    atomicAdd(&lcnt[t], 1);
    __syncthreads();
    if (tid < 16) lbase[tid] = lcnt[tid] ? atomicAdd(&cur[tid], lcnt[tid]) : 0;
    __syncthreads();
    int rank = atomicAdd(&loff[t], 1);
    int pos = lbase[t] + rank;
    eperm[pos] = e;
    srcp[pos] = src[e];
    dstp[pos] = dst[e];
}

// ---------------- fused transform+attention: per 16-edge batch, MFMA transform src/dst rows ----------------
// A-frag: lane holds emb row of edge (l&15), k-slice (l>>4)*8 (layout copied from proven k_gemm_mfma)
// C-frag: lane holds dims cb*16+(l&15) for edges (l>>4)*4+i
__global__ __launch_bounds__(256) void k_edge_attF(const unsigned short* __restrict__ embB,
                                                   const unsigned short* __restrict__ WT,   // [r][n][k] bf16
                                                   const float* __restrict__ rel,           // [r][64]
                                                   const int* __restrict__ srcp,
                                                   const int* __restrict__ dstp,
                                                   const int* __restrict__ eperm,
                                                   const int* __restrict__ roff,            // [17]
                                                   const int* __restrict__ bo,              // [17]
                                                   float* __restrict__ att) {
    __shared__ int sro[17], sbo[17];
    int tid = threadIdx.x;
    if (tid < 17) { sro[tid] = roff[tid]; sbo[tid] = bo[tid]; }
    __syncthreads();
    int w = tid >> 6, l = tid & 63;
    int rlo = l & 15, rhi = l >> 4;
    int gw = blockIdx.x * 4 + w;
    int nw = gridDim.x * 4;
    int NB = sbo[16];
    int per = (NB + nw - 1) / nw;
    int start = gw * per;
    int end = start + per < NB ? start + per : NB;
    if (start >= end) return;

    int r = 0;
    while (sbo[r + 1] <= start) ++r;

    short8 bfr[4][2];
    float relv[4];
    {
        const unsigned short* wt = WT + ((size_t)r << 12);
        #pragma unroll
        for (int cb = 0; cb < 4; ++cb) {
            bfr[cb][0] = *(const short8*)(wt + (cb * 16 + rlo) * 64 + rhi * 8);
            bfr[cb][1] = *(const short8*)(wt + (cb * 16 + rlo) * 64 + 32 + rhi * 8);
            relv[cb] = rel[r * 64 + cb * 16 + rlo];
        }
    }

    for (int g = start; g < end; ++g) {
        if (g >= sbo[r + 1]) {
            while (sbo[r + 1] <= g) ++r;
            const unsigned short* wt = WT + ((size_t)r << 12);
            #pragma unroll
            for (int cb = 0; cb < 4; ++cb) {
                bfr[cb][0] = *(const short8*)(wt + (cb * 16 + rlo) * 64 + rhi * 8);
                bfr[cb][1] = *(const short8*)(wt + (cb * 16 + rlo) * 64 + 32 + rhi * 8);
                relv[cb] = rel[r * 64 + cb * 16 + rlo];
            }
        }
        int i0 = sro[r] + (g - sbo[r]) * 16;
        int hi = sro[r + 1];
        int ea = i0 + rlo; if (ea >= hi) ea = hi - 1;
        size_t sA = (size_t)srcp[ea], sB = (size_t)dstp[ea];
        short8 at0 = *(const short8*)(embB + sA * 64 + rhi * 8);
        short8 at1 = *(const short8*)(embB + sA * 64 + 32 + rhi * 8);
        short8 ah0 = *(const short8*)(embB + sB * 64 + rhi * 8);
        short8 ah1 = *(const short8*)(embB + sB * 64 + 32 + rhi * 8);
        f32x4 accT[4], accH[4];
        #pragma unroll
        for (int cb = 0; cb < 4; ++cb) {
            accT[cb] = (f32x4){0.f, 0.f, 0.f, 0.f};
            accH[cb] = (f32x4){0.f, 0.f, 0.f, 0.f};
            accT[cb] = __builtin_amdgcn_mfma_f32_16x16x32_bf16(at0, bfr[cb][0], accT[cb], 0, 0, 0);
            accT[cb] = __builtin_amdgcn_mfma_f32_16x16x32_bf16(at1, bfr[cb][1], accT[cb], 0, 0, 0);
            accH[cb] = __builtin_amdgcn_mfma_f32_16x16x32_bf16(ah0, bfr[cb][0], accH[cb], 0, 0, 0);
            accH[cb] = __builtin_amdgcn_mfma_f32_16x16x32_bf16(ah1, bfr[cb][1], accH[cb], 0, 0, 0);
        }
        #pragma unroll
        for (int i = 0; i < 4; ++i) {
            float s = 0.f;
            #pragma unroll
            for (int cb = 0; cb < 4; ++cb)
                s += accT[cb][i] * fast_tanh(accH[cb][i] + relv[cb]);
            s += __shfl_xor(s, 1); s += __shfl_xor(s, 2);
            s += __shfl_xor(s, 4); s += __shfl_xor(s, 8);
            int idx = i0 + rhi * 4 + i;
            if (rlo == 0 && idx < hi) att[eperm[idx]] = s;
        }
    }
}

// ---------------- per-dst softmax, 8 lanes per node ----------------
__global__ __launch_bounds__(256) void k_softmax(float* __restrict__ att, const int* __restrict__ offs) {
    int tid = threadIdx.x;
    int n = blockIdx.x * 32 + (tid >> 3);
    int j = tid & 7;
    int b = offs[n], e = offs[n + 1];
    if (b >= e) return;
    float m = -INFINITY;
    for (int i = b + j; i < e; i += 8) m = fmaxf(m, att[i]);
    #pragma unroll
    for (int s = 4; s >= 1; s >>= 1) m = fmaxf(m, __shfl_xor(m, s));
    float sum = 0.f;
    for (int i = b + j; i < e; i += 8) { float v = __expf(att[i] - m); att[i] = v; sum += v; }
    #pragma unroll
    for (int s = 4; s >= 1; s >>= 1) sum += __shfl_xor(sum, s);
    float inv = fast_rcp(sum);
    for (int i = b + j; i < e; i += 8) att[i] *= inv;
}

// ---------------- dense0: Y0 = emb @ W0 AND copy emb block to all 4 results ----------------
__global__ __launch_bounds__(256) void k_dense0(const float* __restrict__ emb,
                                                const float* __restrict__ WLT,   // W0T [32][64]
                                                float* __restrict__ Y0,
                                                float* __restrict__ out) {
    int tid = threadIdx.x, w = tid >> 6, l = tid & 63;
    int c = l & 31, g = l >> 5;
    float Wreg[32];
    #pragma unroll
    for (int kk = 0; kk < 32; ++kk) Wreg[kk] = WLT[(size_t)c * 64 + g * 32 + kk];
    int nw = gridDim.x * 4;
    for (int n = blockIdx.x * 4 + w; n < N_NODES; n += nw) {
        const float* xr = emb + (size_t)n * 64;
        float v = xr[l];
        #pragma unroll
        for (int r = 0; r < 4; ++r)
            out[(size_t)r * RES + (size_t)n * OUTW + l] = v;
        float o = 0.f;
        #pragma unroll
        for (int kk = 0; kk < 32; kk += 4) {
            float4 xv = *(const float4*)(xr + g * 32 + kk);
            o += xv.x * Wreg[kk] + xv.y * Wreg[kk + 1] + xv.z * Wreg[kk + 2] + xv.w * Wreg[kk + 3];
        }
        o += __shfl_xor(o, 32);
        if (l < 32) Y0[(size_t)n * 32 + c] = o;
    }
}

// ---------------- fused layer: u = lrelu(Y[n] + sum att*Y[src] + b); norm->out; Ynext = u @ Wnext ----------------
template<int D, int DN, int COL, int RSTART, bool PROJ>
__global__ __launch_bounds__(256) void k_aggF(const float* __restrict__ Y,
                                              const float* __restrict__ att,
                                              const int* __restrict__ src,
                                              const int* __restrict__ offs,
                                              const float* __restrict__ bias,
                                              const float* __restrict__ WTn,   // next-layer [c][k] fp32
                                              float* __restrict__ Yn,
                                              float* __restrict__ out) {
    constexpr int E = D / 4;              // lanes per edge (float4 each)
    constexpr int S = 64 / E;             // edge slots per wave
    constexpr int G = PROJ ? (64 / DN) : 1;
    constexpr int KS = PROJ ? (D / G) : 1;
    __shared__ float xm[4][PROJ ? D : 4];
    int tid = threadIdx.x, w = tid >> 6, l = tid & 63;
    int n = blockIdx.x * 4 + w;
    int b = offs[n], e = offs[n + 1];
    int je = l & (E - 1), slot = l / E;

    float Wreg[KS];
    if constexpr (PROJ) {
        int c = l & (DN - 1), g = l / DN;
        #pragma unroll
        for (int kk = 0; kk < KS; ++kk) Wreg[kk] = WTn[(size_t)c * D + g * KS + kk];
    }

    float4 a = make_float4(0.f, 0.f, 0.f, 0.f);
    int i = b + slot;
    for (; i + S < e; i += 2 * S) {
        float t0 = att[i], t1 = att[i + S];
        float4 p0 = *(const float4*)(Y + (size_t)src[i]     * D + 4 * je);
        float4 p1 = *(const float4*)(Y + (size_t)src[i + S] * D + 4 * je);
        a.x += t0 * p0.x + t1 * p1.x;
        a.y += t0 * p0.y + t1 * p1.y;
        a.z += t0 * p0.z + t1 * p1.z;
        a.w += t0 * p0.w + t1 * p1.w;
    }
    for (; i < e; i += S) {
        float t0 = att[i];
        float4 p0 = *(const float4*)(Y + (size_t)src[i] * D + 4 * je);
        a.x += t0 * p0.x; a.y += t0 * p0.y; a.z += t0 * p0.z; a.w += t0 * p0.w;
    }
    #pragma unroll
    for (int st = E; st < 64; st <<= 1) {
        a.x += __shfl_xor(a.x, st); a.y += __shfl_xor(a.y, st);
        a.z += __shfl_xor(a.z, st); a.w += __shfl_xor(a.w, st);
    }
    float4 q  = *(const float4*)(Y + (size_t)n * D + 4 * je);
    float4 bi = *(const float4*)(bias + 4 * je);
    float4 u;
    u.x = lrelu(a.x + q.x + bi.x);
    u.y = lrelu(a.y + q.y + bi.y);
    u.z = lrelu(a.z + q.z + bi.z);
    u.w = lrelu(a.w + q.w + bi.w);
    float ss = u.x * u.x + u.y * u.y + u.z * u.z + u.w * u.w;
    #pragma unroll
    for (int st = 1; st < E; st <<= 1) ss += __shfl_xor(ss, st);
    float inv = fast_rcp(fmaxf(sqrtf(ss), 1e-12f));
    if (slot < 4 - RSTART) {
        float4 nr = make_float4(u.x * inv, u.y * inv, u.z * inv, u.w * inv);
        *(float4*)(out + (size_t)(RSTART + slot) * RES + (size_t)n * OUTW + COL + 4 * je) = nr;
    }
    if constexpr (PROJ) {
        if (slot == S - 1) *(float4*)&xm[w][4 * je] = u;
        __builtin_amdgcn_s_waitcnt(0);
        __builtin_amdgcn_sched_barrier(0);
        int c = l & (DN - 1), g = l / DN;
        float o = 0.f;
        if constexpr (KS >= 4) {
            #pragma unroll
            for (int kk = 0; kk < KS; kk += 4) {
                float4 xv = *(const float4*)&xm[w][g * KS + kk];
                o += xv.x * Wreg[kk] + xv.y * Wreg[kk + 1] + xv.z * Wreg[kk + 2] + xv.w * Wreg[kk + 3];
            }
        } else {
            float2 xv = *(const float2*)&xm[w][g * KS];
            o += xv.x * Wreg[0] + xv.y * Wreg[1];
        }
        #pragma unroll
        for (int st = DN; st < 64; st <<= 1) o += __shfl_xor(o, st);
        if (l < DN) Yn[(size_t)n * DN + c] = o;
    }
}

// ---------------- all B-chains in ONE dispatch, using Y shortcuts ----------------
__global__ __launch_bounds__(256) void k_bchain(const float* __restrict__ Y1,
                                                const float* __restrict__ Y2,
                                                const float* __restrict__ Y3,
                                                const float* __restrict__ WLT,
                                                const float* __restrict__ b1,
                                                const float* __restrict__ b2,
                                                const float* __restrict__ b3,
                                                float* __restrict__ out) {
    __shared__ float W2s[16][17], W3s[8][17];
    __shared__ float bb1[16], bb2[16], bb3[8];
    __shared__ float mid[16][17], mid2[16][17];
    int tid = threadIdx.x;
    if (tid < 256) W2s[tid >> 4][tid & 15] = WLT[2560 + tid];
    if (tid < 128) W3s[tid >> 4][tid & 15] = WLT[2816 + tid];
    if (tid < 16) bb1[tid] = b1[tid];
    if (tid >= 32 && tid < 48) bb2[tid - 32] = b2[tid - 32];
    if (tid >= 64 && tid < 72) bb3[tid - 64] = b3[tid - 64];
    __syncthreads();

    int grp = tid >> 4, lj = tid & 15;
    int seg = blockIdx.x / 6250;
    int nb = blockIdx.x % 6250;
    int n = nb * 16 + grp;

    if (seg == 0) {
        float u1 = lrelu(Y1[(size_t)n * 16 + lj] + bb1[lj]);
        mid[grp][lj] = u1;
        float ss = u1 * u1;
        #pragma unroll
        for (int m = 8; m >= 1; m >>= 1) ss += __shfl_xor(ss, m);
        out[(size_t)n * OUTW + 96 + lj] = u1 * fast_rcp(fmaxf(sqrtf(ss), 1e-12f));
        __builtin_amdgcn_s_waitcnt(0);
        __builtin_amdgcn_sched_barrier(0);
        float o2 = bb2[lj];
        #pragma unroll
        for (int k = 0; k < 16; ++k) o2 += mid[grp][k] * W2s[lj][k];
        float u2 = lrelu(o2);
        mid2[grp][lj] = u2;
        float s2 = u2 * u2;
        #pragma unroll
        for (int m = 8; m >= 1; m >>= 1) s2 += __shfl_xor(s2, m);
        out[(size_t)n * OUTW + 112 + lj] = u2 * fast_rcp(fmaxf(sqrtf(s2), 1e-12f));
        __builtin_amdgcn_s_waitcnt(0);
        __builtin_amdgcn_sched_barrier(0);
        if (lj < 8) {
            float o3 = bb3[lj];
            #pragma unroll
            for (int k = 0; k < 16; ++k) o3 += mid2[grp][k] * W3s[lj][k];
            float u3 = lrelu(o3);
            float s3 = u3 * u3;
            #pragma unroll
            for (int m = 4; m >= 1; m >>= 1) s3 += __shfl_xor(s3, m);
            out[(size_t)n * OUTW + 128 + lj] = u3 * fast_rcp(fmaxf(sqrtf(s3), 1e-12f));
        }
    } else if (seg == 1) {
        float u2 = lrelu(Y2[(size_t)n * 16 + lj] + bb2[lj]);
        mid[grp][lj] = u2;
        float s2 = u2 * u2;
        #pragma unroll
        for (int m = 8; m >= 1; m >>= 1) s2 += __shfl_xor(s2, m);
        out[RES + (size_t)n * OUTW + 112 + lj] = u2 * fast_rcp(fmaxf(sqrtf(s2), 1e-12f));
        __builtin_amdgcn_s_waitcnt(0);
        __builtin_amdgcn_sched_barrier(0);
        if (lj < 8) {
            float o3 = bb3[lj];
            #pragma unroll
            for (int k = 0; k < 16; ++k) o3 += mid[grp][k] * W3s[lj][k];
            float u3 = lrelu(o3);
            float s3 = u3 * u3;
            #pragma unroll
            for (int m = 4; m >= 1; m >>= 1) s3 += __shfl_xor(s3, m);
            out[RES + (size_t)n * OUTW + 128 + lj] = u3 * fast_rcp(fmaxf(sqrtf(s3), 1e-12f));
        }
    } else {
        if (lj < 8) {
            float u3 = lrelu(Y3[(size_t)n * 8 + lj] + bb3[lj]);
            float s3 = u3 * u3;
            #pragma unroll
            for (int m = 4; m >= 1; m >>= 1) s3 += __shfl_xor(s3, m);
            out[2 * RES + (size_t)n * OUTW + 128 + lj] = u3 * fast_rcp(fmaxf(sqrtf(s3), 1e-12f));
        }
    }
}

extern "C" void kernel_launch(void* const* d_in, const int* in_sizes, int n_in,
                              void* d_out, int out_size, void* d_ws, size_t ws_size,
                              hipStream_t stream) {
    (void)in_sizes; (void)n_in; (void)out_size; (void)ws_size;
    const float* emb = (const float*)d_in[0];
    const float* rel_embed = (const float*)d_in[1];
    const float* W_R = (const float*)d_in[2];
    const float* W0 = (const float*)d_in[3];  const float* b0 = (const float*)d_in[4];
    const float* W1 = (const float*)d_in[5];  const float* b1 = (const float*)d_in[6];
    const float* W2 = (const float*)d_in[7];  const float* b2 = (const float*)d_in[8];
    const float* W3 = (const float*)d_in[9];  const float* b3 = (const float*)d_in[10];
    const int* src = (const int*)d_in[11];
    const int* dst = (const int*)d_in[12];
    const int* etype = (const int*)d_in[13];
    float* out = (float*)d_out;

    char* p = (char*)d_ws;
    auto alloc = [&](size_t bytes) { char* q = p; p += (bytes + 255) & ~(size_t)255; return q; };
    int* offs  = (int*)alloc((size_t)(N_NODES + 1) * 4);
    float* att = (float*)alloc((size_t)N_EDGES * 4);
    int* eperm = (int*)alloc((size_t)N_EDGES * 4);
    int* srcp  = (int*)alloc((size_t)N_EDGES * 4);
    int* dstp  = (int*)alloc((size_t)N_EDGES * 4);
    int* cnt   = (int*)alloc(64);
    int* roff  = (int*)alloc(68);
    int* cur   = (int*)alloc(64);
    int* bo    = (int*)alloc(68);
    unsigned short* embB = (unsigned short*)alloc((size_t)N_NODES * 64 * 2);
    unsigned short* WT   = (unsigned short*)alloc((size_t)65536 * 2);
    float* WLT = (float*)alloc((size_t)2944 * 4);
    float* Y0  = (float*)alloc((size_t)N_NODES * 32 * 4);
    float* Y1  = (float*)alloc((size_t)N_NODES * 16 * 4);
    float* Y2  = (float*)alloc((size_t)N_NODES * 16 * 4);
    float* Y3  = (float*)alloc((size_t)N_NODES * 8 * 4);

    // fused prep (cast emb, W_R^T, W^T, CSR offsets, zero cnt)
    k_prep<<<6910, 256, 0, stream>>>(emb, embB, W_R, WT, W0, W1, W2, W3, WLT, dst, offs, cnt);
    k_hist<<<N_EDGES / 256, 256, 0, stream>>>(etype, cnt);
    k_scan<<<1, 64, 0, stream>>>(cnt, roff, cur, bo);
    k_scatter<<<N_EDGES / 256, 256, 0, stream>>>(etype, src, dst, cur, eperm, srcp, dstp);

    // fused transform + attention (no materialized per-relation transforms)
    k_edge_attF<<<2048, 256, 0, stream>>>(embB, WT, rel_embed, srcp, dstp, eperm, roff, bo, att);
    k_softmax<<<N_NODES / 32, 256, 0, stream>>>(att, offs);

    // Y0 = emb @ W0 (+ emb block copy into all 4 results)
    k_dense0<<<3125, 256, 0, stream>>>(emb, WLT, Y0, out);

    // A-chain: fused aggregate + bias/lrelu + norm-broadcast + next-layer projection
    k_aggF<32, 16,  64, 0, true ><<<N_NODES / 4, 256, 0, stream>>>(Y0, att, src, offs, b0, WLT + 2048, Y1, out);
    k_aggF<16, 16,  96, 1, true ><<<N_NODES / 4, 256, 0, stream>>>(Y1, att, src, offs, b1, WLT + 2560, Y2, out);
    k_aggF<16,  8, 112, 2, true ><<<N_NODES / 4, 256, 0, stream>>>(Y2, att, src, offs, b2, WLT + 2816, Y3, out);
    k_aggF< 8,  8, 128, 3, false><<<N_NODES / 4, 256, 0, stream>>>(Y3, att, src, offs, b3, nullptr, nullptr, out);

    // all B-chains, one dispatch (first hop of each uses Y shortcut)
    k_bchain<<<18750, 256, 0, stream>>>(Y1, Y2, Y3, WLT, b1, b2, b3, out);
}

// Round 10
// 527.568 us; speedup vs baseline: 1.3775x; 1.0511x over previous
//
#include <hip/hip_runtime.h>
#include <hip/hip_bf16.h>
#include <math.h>

#define N_NODES 100000
#define N_RELS 16
#define N_EDGES 1600000
#define OUTW 136   // 64+32+16+16+8
#define NEG_SLOPE 0.01f
#define RES ((size_t)N_NODES * OUTW)

typedef __attribute__((ext_vector_type(8))) short short8;           // 8 bf16 (4 VGPR)
typedef __attribute__((ext_vector_type(4))) float f32x4;

__device__ __forceinline__ float lrelu(float x) { return x >= 0.f ? x : NEG_SLOPE * x; }
__device__ __forceinline__ float fast_rcp(float x) { return __builtin_amdgcn_rcpf(x); }
__device__ __forceinline__ float fast_tanh(float x) {
    float e = __expf(2.f * x);
    return 1.f - 2.f * fast_rcp(e + 1.f);
}
__device__ __forceinline__ unsigned short f2bf(float f) {
    union { float f; unsigned u; } v; v.f = f;
    unsigned x = v.u + 0x7FFF + ((v.u >> 16) & 1);
    return (unsigned short)(x >> 16);
}

// ---------------- fused prep: cast emb, transpose W_R, transpose layer W, CSR offsets, zero cnt ----------------
__global__ __launch_bounds__(256) void k_prep(const float* __restrict__ emb, unsigned short* __restrict__ embB,
                                              const float* __restrict__ WR, unsigned short* __restrict__ WT,
                                              const float* __restrict__ W0, const float* __restrict__ W1,
                                              const float* __restrict__ W2, const float* __restrict__ W3,
                                              float* __restrict__ WLT,
                                              const int* __restrict__ dst, int* __restrict__ offs,
                                              int* __restrict__ cnt) {
    int blk = blockIdx.x, tid = threadIdx.x;
    if (blk < 6250) {                       // cast emb: 1.6M float4 slots
        int id = blk * 256 + tid;
        float4 v = *(const float4*)(emb + (size_t)id * 4);
        ushort4 o; o.x = f2bf(v.x); o.y = f2bf(v.y); o.z = f2bf(v.z); o.w = f2bf(v.w);
        *(ushort4*)(embB + (size_t)id * 4) = o;
    } else if (blk < 6506) {                // W_R[r][k][n] -> WT[r][n][k] bf16
        int id = (blk - 6250) * 256 + tid;
        int r = id >> 12, rem = id & 4095, n = rem >> 6, k = rem & 63;
        WT[id] = f2bf(WR[(r << 12) + (k << 6) + n]);
    } else if (blk < 6518) {                // layer weights transposed [c][k] fp32
        int id = (blk - 6506) * 256 + tid;
        if (id < 2944) {
            float v;
            if (id < 2048)      { int c = id >> 6, k = id & 63;                  v = W0[k * 32 + c]; }
            else if (id < 2560) { int r = id - 2048; int c = r >> 5, k = r & 31; v = W1[k * 16 + c]; }
            else if (id < 2816) { int r = id - 2560; int c = r >> 4, k = r & 15; v = W2[k * 16 + c]; }
            else                { int r = id - 2816; int c = r >> 4, k = r & 15; v = W3[k * 8 + c]; }
            WLT[id] = v;
        }
    } else if (blk < 6909) {                // CSR offsets (binary search over sorted dst)
        int n = (blk - 6518) * 256 + tid;
        if (n <= N_NODES) {
            int lo = 0, hi = N_EDGES;
            while (lo < hi) { int mid = (lo + hi) >> 1; if (dst[mid] < n) lo = mid + 1; else hi = mid; }
            offs[n] = lo;
        }
    } else {                                // zero relation counters
        if (tid < 16) cnt[tid] = 0;
    }
}

// ---------------- etype histogram / scan / scatter ----------------
__global__ __launch_bounds__(256) void k_hist(const int* __restrict__ etype, int* __restrict__ cnt) {
    __shared__ int lcnt[16];
    int tid = threadIdx.x;
    if (tid < 16) lcnt[tid] = 0;
    __syncthreads();
    atomicAdd(&lcnt[etype[blockIdx.x * 256 + tid]], 1);
    __syncthreads();
    if (tid < 16 && lcnt[tid]) atomicAdd(&cnt[tid], lcnt[tid]);
}

__global__ void k_scan(const int* __restrict__ cnt, int* __restrict__ roff, int* __restrict__ cur) {
    if (threadIdx.x == 0) {
        int a = 0;
        for (int r = 0; r < 16; ++r) { roff[r] = a; cur[r] = a; a += cnt[r]; }
        roff[16] = a;
    }
}

__global__ __launch_bounds__(256) void k_scatter(const int* __restrict__ etype,
                                                 const int* __restrict__ src,
                                                 const int* __restrict__ dst,
                                                 int* __restrict__ cur, int* __restrict__ eperm,
                                                 int* __restrict__ srcp, int* __restrict__ dstp) {
    __shared__ int lcnt[16], lbase[16], loff[16];
    int tid = threadIdx.x;
    if (tid < 16) { lcnt[tid] = 0; loff[tid] = 0; }
    __syncthreads();
    int e = blockIdx.x * 256 + tid;
    int t = etype[e];
    atomicAdd(&lcnt[t], 1);
    __syncthreads();
    if (tid < 16) lbase[tid] = lcnt[tid] ? atomicAdd(&cur[tid], lcnt[tid]) : 0;
    __syncthreads();
    int rank = atomicAdd(&loff[t], 1);
    int pos = lbase[t] + rank;
    eperm[pos] = e;
    srcp[pos] = src[e];
    dstp[pos] = dst[e];
}

// ---------------- fused transform+attention, one relation per 128-block group, 2-deep pipeline ----------------
// A-frag: lane holds emb row of edge (l&15), k-slice (l>>4)*8 (layout from proven k_gemm_mfma)
// C-frag: lane holds dim cb*16+(l&15) for edges (l>>4)*4+i
__global__ __launch_bounds__(256) void k_edge_attF(const unsigned short* __restrict__ embB,
                                                   const unsigned short* __restrict__ WT,   // [r][n][k] bf16
                                                   const float* __restrict__ rel,           // [r][64]
                                                   const int* __restrict__ srcp,
                                                   const int* __restrict__ dstp,
                                                   const int* __restrict__ eperm,
                                                   const int* __restrict__ roff,            // [17]
                                                   float* __restrict__ att) {
    int tid = threadIdx.x, w = tid >> 6, l = tid & 63;
    int rlo = l & 15, rhi = l >> 4;
    int r = blockIdx.x >> 7;                // 128 blocks per relation
    int blk = blockIdx.x & 127;
    int lo = roff[r], hi = roff[r + 1];
    int nb = (hi - lo + 15) >> 4;           // 16-edge batches in this bucket
    constexpr int STEP = 512;               // waves per relation

    // relation weights: B-fragments + rel values, loaded once
    const unsigned short* wt = WT + ((size_t)r << 12);
    short8 bfr[4][2];
    float relv[4];
    #pragma unroll
    for (int cb = 0; cb < 4; ++cb) {
        bfr[cb][0] = *(const short8*)(wt + (cb * 16 + rlo) * 64 + rhi * 8);
        bfr[cb][1] = *(const short8*)(wt + (cb * 16 + rlo) * 64 + 32 + rhi * 8);
        relv[cb] = rel[r * 64 + cb * 16 + rlo];
    }

    int g0 = blk * 4 + w;
    if (g0 >= nb) return;

    auto ldidx = [&](int g, int& sa, int& sb) {
        int ea = lo + g * 16 + rlo;
        if (ea >= hi) ea = hi - 1;
        sa = srcp[ea]; sb = dstp[ea];
    };

    int saC, sbC, saN, sbN;
    ldidx(g0, saC, sbC);
    if (g0 + STEP < nb) ldidx(g0 + STEP, saN, sbN); else { saN = saC; sbN = sbC; }

    // current-batch fragments
    short8 at0 = *(const short8*)(embB + (size_t)saC * 64 + rhi * 8);
    short8 at1 = *(const short8*)(embB + (size_t)saC * 64 + 32 + rhi * 8);
    short8 ah0 = *(const short8*)(embB + (size_t)sbC * 64 + rhi * 8);
    short8 ah1 = *(const short8*)(embB + (size_t)sbC * 64 + 32 + rhi * 8);

    for (int g = g0; g < nb; g += STEP) {
        // prefetch next-batch fragments (indices already resident)
        short8 nt0, nt1, nh0, nh1;
        bool hasn = (g + STEP) < nb;
        if (hasn) {
            nt0 = *(const short8*)(embB + (size_t)saN * 64 + rhi * 8);
            nt1 = *(const short8*)(embB + (size_t)saN * 64 + 32 + rhi * 8);
            nh0 = *(const short8*)(embB + (size_t)sbN * 64 + rhi * 8);
            nh1 = *(const short8*)(embB + (size_t)sbN * 64 + 32 + rhi * 8);
        }
        // prefetch indices 2 batches ahead (into the just-consumed regs)
        if (g + 2 * STEP < nb) ldidx(g + 2 * STEP, saN, sbN);

        f32x4 accT[4], accH[4];
        #pragma unroll
        for (int cb = 0; cb < 4; ++cb) {
            accT[cb] = (f32x4){0.f, 0.f, 0.f, 0.f};
            accH[cb] = (f32x4){0.f, 0.f, 0.f, 0.f};
            accT[cb] = __builtin_amdgcn_mfma_f32_16x16x32_bf16(at0, bfr[cb][0], accT[cb], 0, 0, 0);
            accT[cb] = __builtin_amdgcn_mfma_f32_16x16x32_bf16(at1, bfr[cb][1], accT[cb], 0, 0, 0);
            accH[cb] = __builtin_amdgcn_mfma_f32_16x16x32_bf16(ah0, bfr[cb][0], accH[cb], 0, 0, 0);
            accH[cb] = __builtin_amdgcn_mfma_f32_16x16x32_bf16(ah1, bfr[cb][1], accH[cb], 0, 0, 0);
        }
        int i0 = lo + g * 16;
        #pragma unroll
        for (int i = 0; i < 4; ++i) {
            float s = 0.f;
            #pragma unroll
            for (int cb = 0; cb < 4; ++cb)
                s += accT[cb][i] * fast_tanh(accH[cb][i] + relv[cb]);
            s += __shfl_xor(s, 1); s += __shfl_xor(s, 2);
            s += __shfl_xor(s, 4); s += __shfl_xor(s, 8);
            int idx = i0 + rhi * 4 + i;
            if (rlo == 0 && idx < hi) att[eperm[idx]] = s;
        }
        at0 = nt0; at1 = nt1; ah0 = nh0; ah1 = nh1;
    }
}

// ---------------- per-dst softmax, 8 lanes per node ----------------
__global__ __launch_bounds__(256) void k_softmax(float* __restrict__ att, const int* __restrict__ offs) {
    int tid = threadIdx.x;
    int n = blockIdx.x * 32 + (tid >> 3);
    int j = tid & 7;
    int b = offs[n], e = offs[n + 1];
    if (b >= e) return;
    float m = -INFINITY;
    for (int i = b + j; i < e; i += 8) m = fmaxf(m, att[i]);
    #pragma unroll
    for (int s = 4; s >= 1; s >>= 1) m = fmaxf(m, __shfl_xor(m, s));
    float sum = 0.f;
    for (int i = b + j; i < e; i += 8) { float v = __expf(att[i] - m); att[i] = v; sum += v; }
    #pragma unroll
    for (int s = 4; s >= 1; s >>= 1) sum += __shfl_xor(sum, s);
    float inv = fast_rcp(sum);
    for (int i = b + j; i < e; i += 8) att[i] *= inv;
}

// ---------------- dense0: Y0 = emb @ W0 AND copy emb block to all 4 results ----------------
__global__ __launch_bounds__(256) void k_dense0(const float* __restrict__ emb,
                                                const float* __restrict__ WLT,   // W0T [32][64]
                                                float* __restrict__ Y0,
                                                float* __restrict__ out) {
    int tid = threadIdx.x, w = tid >> 6, l = tid & 63;
    int c = l & 31, g = l >> 5;
    float Wreg[32];
    #pragma unroll
    for (int kk = 0; kk < 32; ++kk) Wreg[kk] = WLT[(size_t)c * 64 + g * 32 + kk];
    int nw = gridDim.x * 4;
    for (int n = blockIdx.x * 4 + w; n < N_NODES; n += nw) {
        const float* xr = emb + (size_t)n * 64;
        float v = xr[l];
        #pragma unroll
        for (int r = 0; r < 4; ++r)
            out[(size_t)r * RES + (size_t)n * OUTW + l] = v;
        float o = 0.f;
        #pragma unroll
        for (int kk = 0; kk < 32; kk += 4) {
            float4 xv = *(const float4*)(xr + g * 32 + kk);
            o += xv.x * Wreg[kk] + xv.y * Wreg[kk + 1] + xv.z * Wreg[kk + 2] + xv.w * Wreg[kk + 3];
        }
        o += __shfl_xor(o, 32);
        if (l < 32) Y0[(size_t)n * 32 + c] = o;
    }
}

// ---------------- fused layer: u = lrelu(Y[n] + sum att*Y[src] + b); norm->out; Ynext = u @ Wnext ----------------
template<int D, int DN, int COL, int RSTART, bool PROJ>
__global__ __launch_bounds__(256) void k_aggF(const float* __restrict__ Y,
                                              const float* __restrict__ att,
                                              const int* __restrict__ src,
                                              const int* __restrict__ offs,
                                              const float* __restrict__ bias,
                                              const float* __restrict__ WTn,   // next-layer [c][k] fp32
                                              float* __restrict__ Yn,
                                              float* __restrict__ out) {
    constexpr int E = D / 4;              // lanes per edge (float4 each)
    constexpr int S = 64 / E;             // edge slots per wave
    constexpr int G = PROJ ? (64 / DN) : 1;
    constexpr int KS = PROJ ? (D / G) : 1;
    __shared__ float xm[4][PROJ ? D : 4];
    int tid = threadIdx.x, w = tid >> 6, l = tid & 63;
    int n = blockIdx.x * 4 + w;
    int b = offs[n], e = offs[n + 1];
    int je = l & (E - 1), slot = l / E;

    float Wreg[KS];
    if constexpr (PROJ) {
        int c = l & (DN - 1), g = l / DN;
        #pragma unroll
        for (int kk = 0; kk < KS; ++kk) Wreg[kk] = WTn[(size_t)c * D + g * KS + kk];
    }

    float4 a = make_float4(0.f, 0.f, 0.f, 0.f);
    int i = b + slot;
    for (; i + S < e; i += 2 * S) {
        float t0 = att[i], t1 = att[i + S];
        float4 p0 = *(const float4*)(Y + (size_t)src[i]     * D + 4 * je);
        float4 p1 = *(const float4*)(Y + (size_t)src[i + S] * D + 4 * je);
        a.x += t0 * p0.x + t1 * p1.x;
        a.y += t0 * p0.y + t1 * p1.y;
        a.z += t0 * p0.z + t1 * p1.z;
        a.w += t0 * p0.w + t1 * p1.w;
    }
    for (; i < e; i += S) {
        float t0 = att[i];
        float4 p0 = *(const float4*)(Y + (size_t)src[i] * D + 4 * je);
        a.x += t0 * p0.x; a.y += t0 * p0.y; a.z += t0 * p0.z; a.w += t0 * p0.w;
    }
    #pragma unroll
    for (int st = E; st < 64; st <<= 1) {
        a.x += __shfl_xor(a.x, st); a.y += __shfl_xor(a.y, st);
        a.z += __shfl_xor(a.z, st); a.w += __shfl_xor(a.w, st);
    }
    float4 q  = *(const float4*)(Y + (size_t)n * D + 4 * je);
    float4 bi = *(const float4*)(bias + 4 * je);
    float4 u;
    u.x = lrelu(a.x + q.x + bi.x);
    u.y = lrelu(a.y + q.y + bi.y);
    u.z = lrelu(a.z + q.z + bi.z);
    u.w = lrelu(a.w + q.w + bi.w);
    float ss = u.x * u.x + u.y * u.y + u.z * u.z + u.w * u.w;
    #pragma unroll
    for (int st = 1; st < E; st <<= 1) ss += __shfl_xor(ss, st);
    float inv = fast_rcp(fmaxf(sqrtf(ss), 1e-12f));
    if (slot < 4 - RSTART) {
        float4 nr = make_float4(u.x * inv, u.y * inv, u.z * inv, u.w * inv);
        *(float4*)(out + (size_t)(RSTART + slot) * RES + (size_t)n * OUTW + COL + 4 * je) = nr;
    }
    if constexpr (PROJ) {
        if (slot == S - 1) *(float4*)&xm[w][4 * je] = u;
        __builtin_amdgcn_s_waitcnt(0);
        __builtin_amdgcn_sched_barrier(0);
        int c = l & (DN - 1), g = l / DN;
        float o = 0.f;
        if constexpr (KS >= 4) {
            #pragma unroll
            for (int kk = 0; kk < KS; kk += 4) {
                float4 xv = *(const float4*)&xm[w][g * KS + kk];
                o += xv.x * Wreg[kk] + xv.y * Wreg[kk + 1] + xv.z * Wreg[kk + 2] + xv.w * Wreg[kk + 3];
            }
        } else {
            float2 xv = *(const float2*)&xm[w][g * KS];
            o += xv.x * Wreg[0] + xv.y * Wreg[1];
        }
        #pragma unroll
        for (int st = DN; st < 64; st <<= 1) o += __shfl_xor(o, st);
        if (l < DN) Yn[(size_t)n * DN + c] = o;
    }
}

// ---------------- all B-chains in ONE dispatch, using Y shortcuts ----------------
__global__ __launch_bounds__(256) void k_bchain(const float* __restrict__ Y1,
                                                const float* __restrict__ Y2,
                                                const float* __restrict__ Y3,
                                                const float* __restrict__ WLT,
                                                const float* __restrict__ b1,
                                                const float* __restrict__ b2,
                                                const float* __restrict__ b3,
                                                float* __restrict__ out) {
    __shared__ float W2s[16][17], W3s[8][17];
    __shared__ float bb1[16], bb2[16], bb3[8];
    __shared__ float mid[16][17], mid2[16][17];
    int tid = threadIdx.x;
    if (tid < 256) W2s[tid >> 4][tid & 15] = WLT[2560 + tid];
    if (tid < 128) W3s[tid >> 4][tid & 15] = WLT[2816 + tid];
    if (tid < 16) bb1[tid] = b1[tid];
    if (tid >= 32 && tid < 48) bb2[tid - 32] = b2[tid - 32];
    if (tid >= 64 && tid < 72) bb3[tid - 64] = b3[tid - 64];
    __syncthreads();

    int grp = tid >> 4, lj = tid & 15;
    int seg = blockIdx.x / 6250;
    int nb = blockIdx.x % 6250;
    int n = nb * 16 + grp;

    if (seg == 0) {
        float u1 = lrelu(Y1[(size_t)n * 16 + lj] + bb1[lj]);
        mid[grp][lj] = u1;
        float ss = u1 * u1;
        #pragma unroll
        for (int m = 8; m >= 1; m >>= 1) ss += __shfl_xor(ss, m);
        out[(size_t)n * OUTW + 96 + lj] = u1 * fast_rcp(fmaxf(sqrtf(ss), 1e-12f));
        __builtin_amdgcn_s_waitcnt(0);
        __builtin_amdgcn_sched_barrier(0);
        float o2 = bb2[lj];
        #pragma unroll
        for (int k = 0; k < 16; ++k) o2 += mid[grp][k] * W2s[lj][k];
        float u2 = lrelu(o2);
        mid2[grp][lj] = u2;
        float s2 = u2 * u2;
        #pragma unroll
        for (int m = 8; m >= 1; m >>= 1) s2 += __shfl_xor(s2, m);
        out[(size_t)n * OUTW + 112 + lj] = u2 * fast_rcp(fmaxf(sqrtf(s2), 1e-12f));
        __builtin_amdgcn_s_waitcnt(0);
        __builtin_amdgcn_sched_barrier(0);
        if (lj < 8) {
            float o3 = bb3[lj];
            #pragma unroll
            for (int k = 0; k < 16; ++k) o3 += mid2[grp][k] * W3s[lj][k];
            float u3 = lrelu(o3);
            float s3 = u3 * u3;
            #pragma unroll
            for (int m = 4; m >= 1; m >>= 1) s3 += __shfl_xor(s3, m);
            out[(size_t)n * OUTW + 128 + lj] = u3 * fast_rcp(fmaxf(sqrtf(s3), 1e-12f));
        }
    } else if (seg == 1) {
        float u2 = lrelu(Y2[(size_t)n * 16 + lj] + bb2[lj]);
        mid[grp][lj] = u2;
        float s2 = u2 * u2;
        #pragma unroll
        for (int m = 8; m >= 1; m >>= 1) s2 += __shfl_xor(s2, m);
        out[RES + (size_t)n * OUTW + 112 + lj] = u2 * fast_rcp(fmaxf(sqrtf(s2), 1e-12f));
        __builtin_amdgcn_s_waitcnt(0);
        __builtin_amdgcn_sched_barrier(0);
        if (lj < 8) {
            float o3 = bb3[lj];
            #pragma unroll
            for (int k = 0; k < 16; ++k) o3 += mid[grp][k] * W3s[lj][k];
            float u3 = lrelu(o3);
            float s3 = u3 * u3;
            #pragma unroll
            for (int m = 4; m >= 1; m >>= 1) s3 += __shfl_xor(s3, m);
            out[RES + (size_t)n * OUTW + 128 + lj] = u3 * fast_rcp(fmaxf(sqrtf(s3), 1e-12f));
        }
    } else {
        if (lj < 8) {
            float u3 = lrelu(Y3[(size_t)n * 8 + lj] + bb3[lj]);
            float s3 = u3 * u3;
            #pragma unroll
            for (int m = 4; m >= 1; m >>= 1) s3 += __shfl_xor(s3, m);
            out[2 * RES + (size_t)n * OUTW + 128 + lj] = u3 * fast_rcp(fmaxf(sqrtf(s3), 1e-12f));
        }
    }
}

extern "C" void kernel_launch(void* const* d_in, const int* in_sizes, int n_in,
                              void* d_out, int out_size, void* d_ws, size_t ws_size,
                              hipStream_t stream) {
    (void)in_sizes; (void)n_in; (void)out_size; (void)ws_size;
    const float* emb = (const float*)d_in[0];
    const float* rel_embed = (const float*)d_in[1];
    const float* W_R = (const float*)d_in[2];
    const float* W0 = (const float*)d_in[3];  const float* b0 = (const float*)d_in[4];
    const float* W1 = (const float*)d_in[5];  const float* b1 = (const float*)d_in[6];
    const float* W2 = (const float*)d_in[7];  const float* b2 = (const float*)d_in[8];
    const float* W3 = (const float*)d_in[9];  const float* b3 = (const float*)d_in[10];
    const int* src = (const int*)d_in[11];
    const int* dst = (const int*)d_in[12];
    const int* etype = (const int*)d_in[13];
    float* out = (float*)d_out;

    char* p = (char*)d_ws;
    auto alloc = [&](size_t bytes) { char* q = p; p += (bytes + 255) & ~(size_t)255; return q; };
    int* offs  = (int*)alloc((size_t)(N_NODES + 1) * 4);
    float* att = (float*)alloc((size_t)N_EDGES * 4);
    int* eperm = (int*)alloc((size_t)N_EDGES * 4);
    int* srcp  = (int*)alloc((size_t)N_EDGES * 4);
    int* dstp  = (int*)alloc((size_t)N_EDGES * 4);
    int* cnt   = (int*)alloc(64);
    int* roff  = (int*)alloc(68);
    int* cur   = (int*)alloc(64);
    unsigned short* embB = (unsigned short*)alloc((size_t)N_NODES * 64 * 2);
    unsigned short* WT   = (unsigned short*)alloc((size_t)65536 * 2);
    float* WLT = (float*)alloc((size_t)2944 * 4);
    float* Y0  = (float*)alloc((size_t)N_NODES * 32 * 4);
    float* Y1  = (float*)alloc((size_t)N_NODES * 16 * 4);
    float* Y2  = (float*)alloc((size_t)N_NODES * 16 * 4);
    float* Y3  = (float*)alloc((size_t)N_NODES * 8 * 4);

    // fused prep (cast emb, W_R^T, W^T, CSR offsets, zero cnt)
    k_prep<<<6910, 256, 0, stream>>>(emb, embB, W_R, WT, W0, W1, W2, W3, WLT, dst, offs, cnt);
    k_hist<<<N_EDGES / 256, 256, 0, stream>>>(etype, cnt);
    k_scan<<<1, 64, 0, stream>>>(cnt, roff, cur);
    k_scatter<<<N_EDGES / 256, 256, 0, stream>>>(etype, src, dst, cur, eperm, srcp, dstp);

    // fused transform + attention: 128 blocks per relation, 2-deep pipelined
    k_edge_attF<<<16 * 128, 256, 0, stream>>>(embB, WT, rel_embed, srcp, dstp, eperm, roff, att);
    k_softmax<<<N_NODES / 32, 256, 0, stream>>>(att, offs);

    // Y0 = emb @ W0 (+ emb block copy into all 4 results)
    k_dense0<<<3125, 256, 0, stream>>>(emb, WLT, Y0, out);

    // A-chain: fused aggregate + bias/lrelu + norm-broadcast + next-layer projection
    k_aggF<32, 16,  64, 0, true ><<<N_NODES / 4, 256, 0, stream>>>(Y0, att, src, offs, b0, WLT + 2048, Y1, out);
    k_aggF<16, 16,  96, 1, true ><<<N_NODES / 4, 256, 0, stream>>>(Y1, att, src, offs, b1, WLT + 2560, Y2, out);
    k_aggF<16,  8, 112, 2, true ><<<N_NODES / 4, 256, 0, stream>>>(Y2, att, src, offs, b2, WLT + 2816, Y3, out);
    k_aggF< 8,  8, 128, 3, false><<<N_NODES / 4, 256, 0, stream>>>(Y3, att, src, offs, b3, nullptr, nullptr, out);

    // all B-chains, one dispatch (first hop of each uses Y shortcut)
    k_bchain<<<18750, 256, 0, stream>>>(Y1, Y2, Y3, WLT, b1, b2, b3, out);
}

// Round 11
// 518.839 us; speedup vs baseline: 1.4006x; 1.0168x over previous
//
#include <hip/hip_runtime.h>
#include <hip/hip_bf16.h>
#include <math.h>

#define N_NODES 100000
#define N_RELS 16
#define N_EDGES 1600000
#define OUTW 136   // 64+32+16+16+8
#define NEG_SLOPE 0.01f
#define RES ((size_t)N_NODES * OUTW)

typedef __attribute__((ext_vector_type(8))) short short8;           // 8 bf16 (4 VGPR)
typedef __attribute__((ext_vector_type(4))) float f32x4;

__device__ __forceinline__ float lrelu(float x) { return x >= 0.f ? x : NEG_SLOPE * x; }
__device__ __forceinline__ float fast_rcp(float x) { return __builtin_amdgcn_rcpf(x); }
__device__ __forceinline__ float fast_tanh(float x) {
    float e = __expf(2.f * x);
    return 1.f - 2.f * fast_rcp(e + 1.f);
}
__device__ __forceinline__ unsigned short f2bf(float f) {
    union { float f; unsigned u; } v; v.f = f;
    unsigned x = v.u + 0x7FFF + ((v.u >> 16) & 1);
    return (unsigned short)(x >> 16);
}

// ---------------- fused prep: cast emb, W_R^T, layer-W^T, CSR offsets, etype hist ----------------
// blocks: [0,6250) cast | [6250,6506) WT | [6506,6518) WLT | [6518,6909) offs | [6909,13159) hist
__global__ __launch_bounds__(256) void k_prep(const float* __restrict__ emb, unsigned short* __restrict__ embB,
                                              const float* __restrict__ WR, unsigned short* __restrict__ WT,
                                              const float* __restrict__ W0, const float* __restrict__ W1,
                                              const float* __restrict__ W2, const float* __restrict__ W3,
                                              float* __restrict__ WLT,
                                              const int* __restrict__ dst, int* __restrict__ offs,
                                              const int* __restrict__ etype, int* __restrict__ cnt) {
    int blk = blockIdx.x, tid = threadIdx.x;
    if (blk < 6250) {
        int id = blk * 256 + tid;
        float4 v = *(const float4*)(emb + (size_t)id * 4);
        ushort4 o; o.x = f2bf(v.x); o.y = f2bf(v.y); o.z = f2bf(v.z); o.w = f2bf(v.w);
        *(ushort4*)(embB + (size_t)id * 4) = o;
    } else if (blk < 6506) {
        int id = (blk - 6250) * 256 + tid;
        int r = id >> 12, rem = id & 4095, n = rem >> 6, k = rem & 63;
        WT[id] = f2bf(WR[(r << 12) + (k << 6) + n]);
    } else if (blk < 6518) {
        int id = (blk - 6506) * 256 + tid;
        if (id < 2944) {
            float v;
            if (id < 2048)      { int c = id >> 6, k = id & 63;                  v = W0[k * 32 + c]; }
            else if (id < 2560) { int r = id - 2048; int c = r >> 5, k = r & 31; v = W1[k * 16 + c]; }
            else if (id < 2816) { int r = id - 2560; int c = r >> 4, k = r & 15; v = W2[k * 16 + c]; }
            else                { int r = id - 2816; int c = r >> 4, k = r & 15; v = W3[k * 8 + c]; }
            WLT[id] = v;
        }
    } else if (blk < 6909) {
        int n = (blk - 6518) * 256 + tid;
        if (n <= N_NODES) {
            int lo = 0, hi = N_EDGES;
            while (lo < hi) { int mid = (lo + hi) >> 1; if (dst[mid] < n) lo = mid + 1; else hi = mid; }
            offs[n] = lo;
        }
    } else {
        __shared__ int lcnt[16];
        if (tid < 16) lcnt[tid] = 0;
        __syncthreads();
        atomicAdd(&lcnt[etype[(blk - 6909) * 256 + tid]], 1);
        __syncthreads();
        if (tid < 16 && lcnt[tid]) atomicAdd(&cnt[tid], lcnt[tid]);
    }
}

__global__ void k_scan(const int* __restrict__ cnt, int* __restrict__ roff, int* __restrict__ cur) {
    if (threadIdx.x == 0) {
        int a = 0;
        for (int r = 0; r < 16; ++r) { roff[r] = a; cur[r] = a; a += cnt[r]; }
        roff[16] = a;
    }
}

__global__ __launch_bounds__(256) void k_scatter(const int* __restrict__ etype,
                                                 const int* __restrict__ src,
                                                 const int* __restrict__ dst,
                                                 int* __restrict__ cur, int* __restrict__ eperm,
                                                 int* __restrict__ srcp, int* __restrict__ dstp) {
    __shared__ int lcnt[16], lbase[16], loff[16];
    int tid = threadIdx.x;
    if (tid < 16) { lcnt[tid] = 0; loff[tid] = 0; }
    __syncthreads();
    int e = blockIdx.x * 256 + tid;
    int t = etype[e];
    atomicAdd(&lcnt[t], 1);
    __syncthreads();
    if (tid < 16) lbase[tid] = lcnt[tid] ? atomicAdd(&cur[tid], lcnt[tid]) : 0;
    __syncthreads();
    int rank = atomicAdd(&loff[t], 1);
    int pos = lbase[t] + rank;
    eperm[pos] = e;
    srcp[pos] = src[e];
    dstp[pos] = dst[e];
}

// ---------------- merged: attention (blocks 0..2047) + dense0/emb-copy (2048..5172) ----------------
__global__ __launch_bounds__(256) void k_att_dense(const unsigned short* __restrict__ embB,
                                                   const unsigned short* __restrict__ WT,
                                                   const float* __restrict__ rel,
                                                   const int* __restrict__ srcp,
                                                   const int* __restrict__ dstp,
                                                   const int* __restrict__ eperm,
                                                   const int* __restrict__ roff,
                                                   float* __restrict__ att,
                                                   const float* __restrict__ emb,
                                                   const float* __restrict__ WLT,
                                                   float* __restrict__ Y0,
                                                   float* __restrict__ out) {
    int tid = threadIdx.x, w = tid >> 6, l = tid & 63;
    if (blockIdx.x < 2048) {
        int rlo = l & 15, rhi = l >> 4;
        int r = blockIdx.x >> 7;
        int blk = blockIdx.x & 127;
        int lo = roff[r], hi = roff[r + 1];
        int nb = (hi - lo + 15) >> 4;
        constexpr int STEP = 512;

        const unsigned short* wt = WT + ((size_t)r << 12);
        short8 bfr[4][2];
        float relv[4];
        #pragma unroll
        for (int cb = 0; cb < 4; ++cb) {
            bfr[cb][0] = *(const short8*)(wt + (cb * 16 + rlo) * 64 + rhi * 8);
            bfr[cb][1] = *(const short8*)(wt + (cb * 16 + rlo) * 64 + 32 + rhi * 8);
            relv[cb] = rel[r * 64 + cb * 16 + rlo];
        }

        int g0 = blk * 4 + w;
        if (g0 >= nb) return;

        auto ldidx = [&](int g, int& sa, int& sb) {
            int ea = lo + g * 16 + rlo;
            if (ea >= hi) ea = hi - 1;
            sa = srcp[ea]; sb = dstp[ea];
        };

        int saC, sbC, saN, sbN;
        ldidx(g0, saC, sbC);
        if (g0 + STEP < nb) ldidx(g0 + STEP, saN, sbN); else { saN = saC; sbN = sbC; }

        short8 at0 = *(const short8*)(embB + (size_t)saC * 64 + rhi * 8);
        short8 at1 = *(const short8*)(embB + (size_t)saC * 64 + 32 + rhi * 8);
        short8 ah0 = *(const short8*)(embB + (size_t)sbC * 64 + rhi * 8);
        short8 ah1 = *(const short8*)(embB + (size_t)sbC * 64 + 32 + rhi * 8);

        for (int g = g0; g < nb; g += STEP) {
            short8 nt0, nt1, nh0, nh1;
            bool hasn = (g + STEP) < nb;
            if (hasn) {
                nt0 = *(const short8*)(embB + (size_t)saN * 64 + rhi * 8);
                nt1 = *(const short8*)(embB + (size_t)saN * 64 + 32 + rhi * 8);
                nh0 = *(const short8*)(embB + (size_t)sbN * 64 + rhi * 8);
                nh1 = *(const short8*)(embB + (size_t)sbN * 64 + 32 + rhi * 8);
            }
            if (g + 2 * STEP < nb) ldidx(g + 2 * STEP, saN, sbN);

            f32x4 accT[4], accH[4];
            #pragma unroll
            for (int cb = 0; cb < 4; ++cb) {
                accT[cb] = (f32x4){0.f, 0.f, 0.f, 0.f};
                accH[cb] = (f32x4){0.f, 0.f, 0.f, 0.f};
                accT[cb] = __builtin_amdgcn_mfma_f32_16x16x32_bf16(at0, bfr[cb][0], accT[cb], 0, 0, 0);
                accT[cb] = __builtin_amdgcn_mfma_f32_16x16x32_bf16(at1, bfr[cb][1], accT[cb], 0, 0, 0);
                accH[cb] = __builtin_amdgcn_mfma_f32_16x16x32_bf16(ah0, bfr[cb][0], accH[cb], 0, 0, 0);
                accH[cb] = __builtin_amdgcn_mfma_f32_16x16x32_bf16(ah1, bfr[cb][1], accH[cb], 0, 0, 0);
            }
            int i0 = lo + g * 16;
            #pragma unroll
            for (int i = 0; i < 4; ++i) {
                float s = 0.f;
                #pragma unroll
                for (int cb = 0; cb < 4; ++cb)
                    s += accT[cb][i] * fast_tanh(accH[cb][i] + relv[cb]);
                s += __shfl_xor(s, 1); s += __shfl_xor(s, 2);
                s += __shfl_xor(s, 4); s += __shfl_xor(s, 8);
                int idx = i0 + rhi * 4 + i;
                if (rlo == 0 && idx < hi) att[eperm[idx]] = s;
            }
            at0 = nt0; at1 = nt1; ah0 = nh0; ah1 = nh1;
        }
    } else {
        int bid = blockIdx.x - 2048;       // 3125 blocks
        int c = l & 31, g = l >> 5;
        float Wreg[32];
        #pragma unroll
        for (int kk = 0; kk < 32; ++kk) Wreg[kk] = WLT[(size_t)c * 64 + g * 32 + kk];
        for (int n = bid * 4 + w; n < N_NODES; n += 12500) {
            const float* xr = emb + (size_t)n * 64;
            float v = xr[l];
            #pragma unroll
            for (int r = 0; r < 4; ++r)
                out[(size_t)r * RES + (size_t)n * OUTW + l] = v;
            float o = 0.f;
            #pragma unroll
            for (int kk = 0; kk < 32; kk += 4) {
                float4 xv = *(const float4*)(xr + g * 32 + kk);
                o += xv.x * Wreg[kk] + xv.y * Wreg[kk + 1] + xv.z * Wreg[kk + 2] + xv.w * Wreg[kk + 3];
            }
            o += __shfl_xor(o, 32);
            if (l < 32) Y0[(size_t)n * 32 + c] = o;
        }
    }
}

// ---------------- layer 1 with FUSED softmax: raw att in, normalized attn out ----------------
__global__ __launch_bounds__(256) void k_aggF1(const float* __restrict__ Y,
                                               const float* __restrict__ att,
                                               float* __restrict__ attn,
                                               const int* __restrict__ src,
                                               const int* __restrict__ offs,
                                               const float* __restrict__ bias,
                                               const float* __restrict__ WTn,
                                               float* __restrict__ Yn,
                                               float* __restrict__ out) {
    constexpr int D = 32, DN = 16, E = 8, S = 8, KS = 8;
    __shared__ float xm[4][D];
    int tid = threadIdx.x, w = tid >> 6, l = tid & 63;
    int n = blockIdx.x * 4 + w;
    int b = offs[n], e = offs[n + 1];
    int je = l & (E - 1), slot = l / E;
    int c = l & (DN - 1), g = l / DN;

    float Wreg[KS];
    #pragma unroll
    for (int kk = 0; kk < KS; ++kk) Wreg[kk] = WTn[(size_t)c * D + g * KS + kk];

    float m = -INFINITY;
    for (int i = b + l; i < e; i += 64) m = fmaxf(m, att[i]);
    #pragma unroll
    for (int st = 32; st >= 1; st >>= 1) m = fmaxf(m, __shfl_xor(m, st));
    float sum = 0.f;
    for (int i = b + l; i < e; i += 64) sum += __expf(att[i] - m);
    #pragma unroll
    for (int st = 32; st >= 1; st >>= 1) sum += __shfl_xor(sum, st);
    float inv = fast_rcp(sum);

    float4 a = make_float4(0.f, 0.f, 0.f, 0.f);
    int i = b + slot;
    for (; i + S < e; i += 2 * S) {
        float t0 = __expf(att[i] - m) * inv, t1 = __expf(att[i + S] - m) * inv;
        if (je == 0) { attn[i] = t0; attn[i + S] = t1; }
        float4 p0 = *(const float4*)(Y + (size_t)src[i]     * D + 4 * je);
        float4 p1 = *(const float4*)(Y + (size_t)src[i + S] * D + 4 * je);
        a.x += t0 * p0.x + t1 * p1.x;
        a.y += t0 * p0.y + t1 * p1.y;
        a.z += t0 * p0.z + t1 * p1.z;
        a.w += t0 * p0.w + t1 * p1.w;
    }
    for (; i < e; i += S) {
        float t0 = __expf(att[i] - m) * inv;
        if (je == 0) attn[i] = t0;
        float4 p0 = *(const float4*)(Y + (size_t)src[i] * D + 4 * je);
        a.x += t0 * p0.x; a.y += t0 * p0.y; a.z += t0 * p0.z; a.w += t0 * p0.w;
    }
    #pragma unroll
    for (int st = E; st < 64; st <<= 1) {
        a.x += __shfl_xor(a.x, st); a.y += __shfl_xor(a.y, st);
        a.z += __shfl_xor(a.z, st); a.w += __shfl_xor(a.w, st);
    }
    float4 q  = *(const float4*)(Y + (size_t)n * D + 4 * je);
    float4 bi = *(const float4*)(bias + 4 * je);
    float4 u;
    u.x = lrelu(a.x + q.x + bi.x);
    u.y = lrelu(a.y + q.y + bi.y);
    u.z = lrelu(a.z + q.z + bi.z);
    u.w = lrelu(a.w + q.w + bi.w);
    float ss = u.x * u.x + u.y * u.y + u.z * u.z + u.w * u.w;
    #pragma unroll
    for (int st = 1; st < E; st <<= 1) ss += __shfl_xor(ss, st);
    float nv = fast_rcp(fmaxf(sqrtf(ss), 1e-12f));
    if (slot < 4) {
        float4 nr = make_float4(u.x * nv, u.y * nv, u.z * nv, u.w * nv);
        *(float4*)(out + (size_t)slot * RES + (size_t)n * OUTW + 64 + 4 * je) = nr;
    }
    if (slot == S - 1) *(float4*)&xm[w][4 * je] = u;
    __builtin_amdgcn_s_waitcnt(0);
    __builtin_amdgcn_sched_barrier(0);
    float o = 0.f;
    #pragma unroll
    for (int kk = 0; kk < KS; kk += 4) {
        float4 xv = *(const float4*)&xm[w][g * KS + kk];
        o += xv.x * Wreg[kk] + xv.y * Wreg[kk + 1] + xv.z * Wreg[kk + 2] + xv.w * Wreg[kk + 3];
    }
    #pragma unroll
    for (int st = DN; st < 64; st <<= 1) o += __shfl_xor(o, st);
    if (l < DN) Yn[(size_t)n * DN + c] = o;
}

// ---------------- fused layer (normalized attn in) ----------------
template<int D, int DN, int COL, int RSTART, bool PROJ>
__global__ __launch_bounds__(256) void k_aggF(const float* __restrict__ Y,
                                              const float* __restrict__ att,
                                              const int* __restrict__ src,
                                              const int* __restrict__ offs,
                                              const float* __restrict__ bias,
                                              const float* __restrict__ WTn,
                                              float* __restrict__ Yn,
                                              float* __restrict__ out) {
    constexpr int E = D / 4;
    constexpr int S = 64 / E;
    constexpr int G = PROJ ? (64 / DN) : 1;
    constexpr int KS = PROJ ? (D / G) : 1;
    __shared__ float xm[4][PROJ ? D : 4];
    int tid = threadIdx.x, w = tid >> 6, l = tid & 63;
    int n = blockIdx.x * 4 + w;
    int b = offs[n], e = offs[n + 1];
    int je = l & (E - 1), slot = l / E;

    float Wreg[KS];
    if constexpr (PROJ) {
        int c = l & (DN - 1), g = l / DN;
        #pragma unroll
        for (int kk = 0; kk < KS; ++kk) Wreg[kk] = WTn[(size_t)c * D + g * KS + kk];
    }

    float4 a = make_float4(0.f, 0.f, 0.f, 0.f);
    int i = b + slot;
    for (; i + S < e; i += 2 * S) {
        float t0 = att[i], t1 = att[i + S];
        float4 p0 = *(const float4*)(Y + (size_t)src[i]     * D + 4 * je);
        float4 p1 = *(const float4*)(Y + (size_t)src[i + S] * D + 4 * je);
        a.x += t0 * p0.x + t1 * p1.x;
        a.y += t0 * p0.y + t1 * p1.y;
        a.z += t0 * p0.z + t1 * p1.z;
        a.w += t0 * p0.w + t1 * p1.w;
    }
    for (; i < e; i += S) {
        float t0 = att[i];
        float4 p0 = *(const float4*)(Y + (size_t)src[i] * D + 4 * je);
        a.x += t0 * p0.x; a.y += t0 * p0.y; a.z += t0 * p0.z; a.w += t0 * p0.w;
    }
    #pragma unroll
    for (int st = E; st < 64; st <<= 1) {
        a.x += __shfl_xor(a.x, st); a.y += __shfl_xor(a.y, st);
        a.z += __shfl_xor(a.z, st); a.w += __shfl_xor(a.w, st);
    }
    float4 q  = *(const float4*)(Y + (size_t)n * D + 4 * je);
    float4 bi = *(const float4*)(bias + 4 * je);
    float4 u;
    u.x = lrelu(a.x + q.x + bi.x);
    u.y = lrelu(a.y + q.y + bi.y);
    u.z = lrelu(a.z + q.z + bi.z);
    u.w = lrelu(a.w + q.w + bi.w);
    float ss = u.x * u.x + u.y * u.y + u.z * u.z + u.w * u.w;
    #pragma unroll
    for (int st = 1; st < E; st <<= 1) ss += __shfl_xor(ss, st);
    float inv = fast_rcp(fmaxf(sqrtf(ss), 1e-12f));
    if (slot < 4 - RSTART) {
        float4 nr = make_float4(u.x * inv, u.y * inv, u.z * inv, u.w * inv);
        *(float4*)(out + (size_t)(RSTART + slot) * RES + (size_t)n * OUTW + COL + 4 * je) = nr;
    }
    if constexpr (PROJ) {
        if (slot == S - 1) *(float4*)&xm[w][4 * je] = u;
        __builtin_amdgcn_s_waitcnt(0);
        __builtin_amdgcn_sched_barrier(0);
        int c = l & (DN - 1), g = l / DN;
        float o = 0.f;
        if constexpr (KS >= 4) {
            #pragma unroll
            for (int kk = 0; kk < KS; kk += 4) {
                float4 xv = *(const float4*)&xm[w][g * KS + kk];
                o += xv.x * Wreg[kk] + xv.y * Wreg[kk + 1] + xv.z * Wreg[kk + 2] + xv.w * Wreg[kk + 3];
            }
        } else {
            float2 xv = *(const float2*)&xm[w][g * KS];
            o += xv.x * Wreg[0] + xv.y * Wreg[1];
        }
        #pragma unroll
        for (int st = DN; st < 64; st <<= 1) o += __shfl_xor(o, st);
        if (l < DN) Yn[(size_t)n * DN + c] = o;
    }
}

// ---------------- merged tail: aggF<8,8,128,3> (blocks 0..24999) + B-chains (25000..43749) ----------------
__global__ __launch_bounds__(256) void k_tail(const float* __restrict__ Y3,
                                              const float* __restrict__ attn,
                                              const int* __restrict__ src,
                                              const int* __restrict__ offs,
                                              const float* __restrict__ b3v,
                                              const float* __restrict__ Y1,
                                              const float* __restrict__ Y2,
                                              const float* __restrict__ WLT,
                                              const float* __restrict__ b1,
                                              const float* __restrict__ b2,
                                              float* __restrict__ out) {
    int tid = threadIdx.x;
    if (blockIdx.x < 25000) {
        constexpr int D = 8, E = 2, S = 32;
        int w = tid >> 6, l = tid & 63;
        int n = blockIdx.x * 4 + w;
        int b = offs[n], e = offs[n + 1];
        int je = l & (E - 1), slot = l / E;
        float4 a = make_float4(0.f, 0.f, 0.f, 0.f);
        int i = b + slot;
        for (; i + S < e; i += 2 * S) {
            float t0 = attn[i], t1 = attn[i + S];
            float4 p0 = *(const float4*)(Y3 + (size_t)src[i]     * D + 4 * je);
            float4 p1 = *(const float4*)(Y3 + (size_t)src[i + S] * D + 4 * je);
            a.x += t0 * p0.x + t1 * p1.x;
            a.y += t0 * p0.y + t1 * p1.y;
            a.z += t0 * p0.z + t1 * p1.z;
            a.w += t0 * p0.w + t1 * p1.w;
        }
        for (; i < e; i += S) {
            float t0 = attn[i];
            float4 p0 = *(const float4*)(Y3 + (size_t)src[i] * D + 4 * je);
            a.x += t0 * p0.x; a.y += t0 * p0.y; a.z += t0 * p0.z; a.w += t0 * p0.w;
        }
        #pragma unroll
        for (int st = E; st < 64; st <<= 1) {
            a.x += __shfl_xor(a.x, st); a.y += __shfl_xor(a.y, st);
            a.z += __shfl_xor(a.z, st); a.w += __shfl_xor(a.w, st);
        }
        float4 q  = *(const float4*)(Y3 + (size_t)n * D + 4 * je);
        float4 bi = *(const float4*)(b3v + 4 * je);
        float4 u;
        u.x = lrelu(a.x + q.x + bi.x);
        u.y = lrelu(a.y + q.y + bi.y);
        u.z = lrelu(a.z + q.z + bi.z);
        u.w = lrelu(a.w + q.w + bi.w);
        float ss = u.x * u.x + u.y * u.y + u.z * u.z + u.w * u.w;
        ss += __shfl_xor(ss, 1);
        float inv = fast_rcp(fmaxf(sqrtf(ss), 1e-12f));
        if (slot < 1) {
            float4 nr = make_float4(u.x * inv, u.y * inv, u.z * inv, u.w * inv);
            *(float4*)(out + 3 * RES + (size_t)n * OUTW + 128 + 4 * je) = nr;
        }
    } else {
        __shared__ float W2s[16][17], W3s[8][17];
        __shared__ float bb1[16], bb2[16], bb3[8];
        __shared__ float mid[16][17], mid2[16][17];
        if (tid < 256) W2s[tid >> 4][tid & 15] = WLT[2560 + tid];
        if (tid < 128) W3s[tid >> 4][tid & 15] = WLT[2816 + tid];
        if (tid < 16) bb1[tid] = b1[tid];
        if (tid >= 32 && tid < 48) bb2[tid - 32] = b2[tid - 32];
        if (tid >= 64 && tid < 72) bb3[tid - 64] = b3v[tid - 64];
        __syncthreads();

        int grp = tid >> 4, lj = tid & 15;
        int bid = blockIdx.x - 25000;
        int seg = bid / 6250;
        int nb = bid % 6250;
        int n = nb * 16 + grp;

        if (seg == 0) {
            float u1 = lrelu(Y1[(size_t)n * 16 + lj] + bb1[lj]);
            mid[grp][lj] = u1;
            float ss = u1 * u1;
            #pragma unroll
            for (int m = 8; m >= 1; m >>= 1) ss += __shfl_xor(ss, m);
            out[(size_t)n * OUTW + 96 + lj] = u1 * fast_rcp(fmaxf(sqrtf(ss), 1e-12f));
            __builtin_amdgcn_s_waitcnt(0);
            __builtin_amdgcn_sched_barrier(0);
            float o2 = bb2[lj];
            #pragma unroll
            for (int k = 0; k < 16; ++k) o2 += mid[grp][k] * W2s[lj][k];
            float u2 = lrelu(o2);
            mid2[grp][lj] = u2;
            float s2 = u2 * u2;
            #pragma unroll
            for (int m = 8; m >= 1; m >>= 1) s2 += __shfl_xor(s2, m);
            out[(size_t)n * OUTW + 112 + lj] = u2 * fast_rcp(fmaxf(sqrtf(s2), 1e-12f));
            __builtin_amdgcn_s_waitcnt(0);
            __builtin_amdgcn_sched_barrier(0);
            if (lj < 8) {
                float o3 = bb3[lj];
                #pragma unroll
                for (int k = 0; k < 16; ++k) o3 += mid2[grp][k] * W3s[lj][k];
                float u3 = lrelu(o3);
                float s3 = u3 * u3;
                #pragma unroll
                for (int m = 4; m >= 1; m >>= 1) s3 += __shfl_xor(s3, m);
                out[(size_t)n * OUTW + 128 + lj] = u3 * fast_rcp(fmaxf(sqrtf(s3), 1e-12f));
            }
        } else if (seg == 1) {
            float u2 = lrelu(Y2[(size_t)n * 16 + lj] + bb2[lj]);
            mid[grp][lj] = u2;
            float s2 = u2 * u2;
            #pragma unroll
            for (int m = 8; m >= 1; m >>= 1) s2 += __shfl_xor(s2, m);
            out[RES + (size_t)n * OUTW + 112 + lj] = u2 * fast_rcp(fmaxf(sqrtf(s2), 1e-12f));
            __builtin_amdgcn_s_waitcnt(0);
            __builtin_amdgcn_sched_barrier(0);
            if (lj < 8) {
                float o3 = bb3[lj];
                #pragma unroll
                for (int k = 0; k < 16; ++k) o3 += mid[grp][k] * W3s[lj][k];
                float u3 = lrelu(o3);
                float s3 = u3 * u3;
                #pragma unroll
                for (int m = 4; m >= 1; m >>= 1) s3 += __shfl_xor(s3, m);
                out[RES + (size_t)n * OUTW + 128 + lj] = u3 * fast_rcp(fmaxf(sqrtf(s3), 1e-12f));
            }
        } else {
            if (lj < 8) {
                float u3 = lrelu(Y3[(size_t)n * 8 + lj] + bb3[lj]);
                float s3 = u3 * u3;
                #pragma unroll
                for (int m = 4; m >= 1; m >>= 1) s3 += __shfl_xor(s3, m);
                out[2 * RES + (size_t)n * OUTW + 128 + lj] = u3 * fast_rcp(fmaxf(sqrtf(s3), 1e-12f));
            }
        }
    }
}

extern "C" void kernel_launch(void* const* d_in, const int* in_sizes, int n_in,
                              void* d_out, int out_size, void* d_ws, size_t ws_size,
                              hipStream_t stream) {
    (void)in_sizes; (void)n_in; (void)out_size; (void)ws_size;
    const float* emb = (const float*)d_in[0];
    const float* rel_embed = (const float*)d_in[1];
    const float* W_R = (const float*)d_in[2];
    const float* W0 = (const float*)d_in[3];  const float* b0 = (const float*)d_in[4];
    const float* W1 = (const float*)d_in[5];  const float* b1 = (const float*)d_in[6];
    const float* W2 = (const float*)d_in[7];  const float* b2 = (const float*)d_in[8];
    const float* W3 = (const float*)d_in[9];  const float* b3 = (const float*)d_in[10];
    const int* src = (const int*)d_in[11];
    const int* dst = (const int*)d_in[12];
    const int* etype = (const int*)d_in[13];
    float* out = (float*)d_out;

    char* p = (char*)d_ws;
    auto alloc = [&](size_t bytes) { char* q = p; p += (bytes + 255) & ~(size_t)255; return q; };
    int* offs  = (int*)alloc((size_t)(N_NODES + 1) * 4);
    float* att = (float*)alloc((size_t)N_EDGES * 4);
    float* attn = (float*)alloc((size_t)N_EDGES * 4);
    int* eperm = (int*)alloc((size_t)N_EDGES * 4);
    int* srcp  = (int*)alloc((size_t)N_EDGES * 4);
    int* dstp  = (int*)alloc((size_t)N_EDGES * 4);
    int* cnt   = (int*)alloc(64);
    int* roff  = (int*)alloc(68);
    int* cur   = (int*)alloc(64);
    unsigned short* embB = (unsigned short*)alloc((size_t)N_NODES * 64 * 2);
    unsigned short* WT   = (unsigned short*)alloc((size_t)65536 * 2);
    float* WLT = (float*)alloc((size_t)2944 * 4);
    float* Y0  = (float*)alloc((size_t)N_NODES * 32 * 4);
    float* Y1  = (float*)alloc((size_t)N_NODES * 16 * 4);
    float* Y2  = (float*)alloc((size_t)N_NODES * 16 * 4);
    float* Y3  = (float*)alloc((size_t)N_NODES * 8 * 4);

    hipMemsetAsync(cnt, 0, 64, stream);
    // fused prep (cast emb, W_R^T, W^T, CSR offsets, etype hist)
    k_prep<<<13159, 256, 0, stream>>>(emb, embB, W_R, WT, W0, W1, W2, W3, WLT, dst, offs, etype, cnt);
    k_scan<<<1, 64, 0, stream>>>(cnt, roff, cur);
    k_scatter<<<N_EDGES / 256, 256, 0, stream>>>(etype, src, dst, cur, eperm, srcp, dstp);

    // attention (2048 blocks) + dense0/emb-copy (3125 blocks) in one dispatch
    k_att_dense<<<2048 + 3125, 256, 0, stream>>>(embB, WT, rel_embed, srcp, dstp, eperm, roff, att,
                                                 emb, WLT, Y0, out);

    // layer 1 with fused softmax (writes normalized attn for layers 2-4)
    k_aggF1<<<N_NODES / 4, 256, 0, stream>>>(Y0, att, attn, src, offs, b0, WLT + 2048, Y1, out);
    k_aggF<16, 16,  96, 1, true ><<<N_NODES / 4, 256, 0, stream>>>(Y1, attn, src, offs, b1, WLT + 2560, Y2, out);
    k_aggF<16,  8, 112, 2, true ><<<N_NODES / 4, 256, 0, stream>>>(Y2, attn, src, offs, b2, WLT + 2816, Y3, out);

    // last aggregation layer + all B-chains in one dispatch
    k_tail<<<25000 + 18750, 256, 0, stream>>>(Y3, attn, src, offs, b3, Y1, Y2, WLT, b1, b2, out);
}

// Round 13
// 512.599 us; speedup vs baseline: 1.4177x; 1.0122x over previous
//
#include <hip/hip_runtime.h>
#include <hip/hip_bf16.h>
#include <math.h>

#define N_NODES 100000
#define N_RELS 16
#define N_EDGES 1600000
#define OUTW 136   // 64+32+16+16+8
#define NEG_SLOPE 0.01f
#define RES ((size_t)N_NODES * OUTW)

typedef __attribute__((ext_vector_type(8))) short short8;           // 8 bf16 (4 VGPR)
typedef __attribute__((ext_vector_type(4))) float f32x4;

__device__ __forceinline__ float lrelu(float x) { return x >= 0.f ? x : NEG_SLOPE * x; }
__device__ __forceinline__ float fast_rcp(float x) { return __builtin_amdgcn_rcpf(x); }
__device__ __forceinline__ float fast_tanh(float x) {
    float e = __expf(2.f * x);
    return 1.f - 2.f * fast_rcp(e + 1.f);
}
__device__ __forceinline__ unsigned short f2bf(float f) {
    union { float f; unsigned u; } v; v.f = f;
    unsigned x = v.u + 0x7FFF + ((v.u >> 16) & 1);
    return (unsigned short)(x >> 16);
}
__device__ __forceinline__ void nt_store4(float* p, float4 v) {
    f32x4 t; t[0] = v.x; t[1] = v.y; t[2] = v.z; t[3] = v.w;
    __builtin_nontemporal_store(t, (f32x4*)p);
}
__device__ __forceinline__ void nt_store1(float* p, float v) { __builtin_nontemporal_store(v, p); }

// ---------------- fused prep: cast emb, W_R^T, layer-W^T, CSR offsets, etype hist ----------------
// blocks: [0,6250) cast | [6250,6506) WT | [6506,6518) WLT | [6518,6909) offs | [6909,13159) hist
__global__ __launch_bounds__(256) void k_prep(const float* __restrict__ emb, unsigned short* __restrict__ embB,
                                              const float* __restrict__ WR, unsigned short* __restrict__ WT,
                                              const float* __restrict__ W0, const float* __restrict__ W1,
                                              const float* __restrict__ W2, const float* __restrict__ W3,
                                              float* __restrict__ WLT,
                                              const int* __restrict__ dst, int* __restrict__ offs,
                                              const int* __restrict__ etype, int* __restrict__ cnt) {
    int blk = blockIdx.x, tid = threadIdx.x;
    if (blk < 6250) {
        int id = blk * 256 + tid;
        float4 v = *(const float4*)(emb + (size_t)id * 4);
        ushort4 o; o.x = f2bf(v.x); o.y = f2bf(v.y); o.z = f2bf(v.z); o.w = f2bf(v.w);
        *(ushort4*)(embB + (size_t)id * 4) = o;
    } else if (blk < 6506) {
        int id = (blk - 6250) * 256 + tid;
        int r = id >> 12, rem = id & 4095, n = rem >> 6, k = rem & 63;
        WT[id] = f2bf(WR[(r << 12) + (k << 6) + n]);
    } else if (blk < 6518) {
        int id = (blk - 6506) * 256 + tid;
        if (id < 2944) {
            float v;
            if (id < 2048)      { int c = id >> 6, k = id & 63;                  v = W0[k * 32 + c]; }
            else if (id < 2560) { int r = id - 2048; int c = r >> 5, k = r & 31; v = W1[k * 16 + c]; }
            else if (id < 2816) { int r = id - 2560; int c = r >> 4, k = r & 15; v = W2[k * 16 + c]; }
            else                { int r = id - 2816; int c = r >> 4, k = r & 15; v = W3[k * 8 + c]; }
            WLT[id] = v;
        }
    } else if (blk < 6909) {
        int n = (blk - 6518) * 256 + tid;
        if (n <= N_NODES) {
            int lo = 0, hi = N_EDGES;
            while (lo < hi) { int mid = (lo + hi) >> 1; if (dst[mid] < n) lo = mid + 1; else hi = mid; }
            offs[n] = lo;
        }
    } else {
        __shared__ int lcnt[16];
        if (tid < 16) lcnt[tid] = 0;
        __syncthreads();
        atomicAdd(&lcnt[etype[(blk - 6909) * 256 + tid]], 1);
        __syncthreads();
        if (tid < 16 && lcnt[tid]) atomicAdd(&cnt[tid], lcnt[tid]);
    }
}

__global__ void k_scan(const int* __restrict__ cnt, int* __restrict__ roff, int* __restrict__ cur) {
    if (threadIdx.x == 0) {
        int a = 0;
        for (int r = 0; r < 16; ++r) { roff[r] = a; cur[r] = a; a += cnt[r]; }
        roff[16] = a;
    }
}

__global__ __launch_bounds__(256) void k_scatter(const int* __restrict__ etype,
                                                 const int* __restrict__ src,
                                                 const int* __restrict__ dst,
                                                 int* __restrict__ cur, int* __restrict__ eperm,
                                                 int* __restrict__ srcp, int* __restrict__ dstp) {
    __shared__ int lcnt[16], lbase[16], loff[16];
    int tid = threadIdx.x;
    if (tid < 16) { lcnt[tid] = 0; loff[tid] = 0; }
    __syncthreads();
    int e = blockIdx.x * 256 + tid;
    int t = etype[e];
    atomicAdd(&lcnt[t], 1);
    __syncthreads();
    if (tid < 16) lbase[tid] = lcnt[tid] ? atomicAdd(&cur[tid], lcnt[tid]) : 0;
    __syncthreads();
    int rank = atomicAdd(&loff[t], 1);
    int pos = lbase[t] + rank;
    eperm[pos] = e;
    srcp[pos] = src[e];
    dstp[pos] = dst[e];
}

// ---------------- merged: attention (blocks 0..4095, 256/relation) + dense0/emb-copy (4096..7220) ----------------
__global__ __launch_bounds__(256) void k_att_dense(const unsigned short* __restrict__ embB,
                                                   const unsigned short* __restrict__ WT,
                                                   const float* __restrict__ rel,
                                                   const int* __restrict__ srcp,
                                                   const int* __restrict__ dstp,
                                                   const int* __restrict__ eperm,
                                                   const int* __restrict__ roff,
                                                   float* __restrict__ att,
                                                   const float* __restrict__ emb,
                                                   const float* __restrict__ WLT,
                                                   float* __restrict__ Y0,
                                                   float* __restrict__ out) {
    int tid = threadIdx.x, w = tid >> 6, l = tid & 63;
    if (blockIdx.x < 4096) {
        int rlo = l & 15, rhi = l >> 4;
        int r = blockIdx.x >> 8;            // 256 blocks per relation
        int blk = blockIdx.x & 255;
        int lo = roff[r], hi = roff[r + 1];
        int nb = (hi - lo + 15) >> 4;
        constexpr int STEP = 1024;          // waves per relation

        const unsigned short* wt = WT + ((size_t)r << 12);
        short8 bfr[4][2];
        float relv[4];
        #pragma unroll
        for (int cb = 0; cb < 4; ++cb) {
            bfr[cb][0] = *(const short8*)(wt + (cb * 16 + rlo) * 64 + rhi * 8);
            bfr[cb][1] = *(const short8*)(wt + (cb * 16 + rlo) * 64 + 32 + rhi * 8);
            relv[cb] = rel[r * 64 + cb * 16 + rlo];
        }

        int g0 = blk * 4 + w;
        if (g0 >= nb) return;

        auto ldidx = [&](int g, int& sa, int& sb) {
            int ea = lo + g * 16 + rlo;
            if (ea >= hi) ea = hi - 1;
            sa = srcp[ea]; sb = dstp[ea];
        };

        int saC, sbC, saN, sbN;
        ldidx(g0, saC, sbC);
        if (g0 + STEP < nb) ldidx(g0 + STEP, saN, sbN); else { saN = saC; sbN = sbC; }

        short8 at0 = *(const short8*)(embB + (size_t)saC * 64 + rhi * 8);
        short8 at1 = *(const short8*)(embB + (size_t)saC * 64 + 32 + rhi * 8);
        short8 ah0 = *(const short8*)(embB + (size_t)sbC * 64 + rhi * 8);
        short8 ah1 = *(const short8*)(embB + (size_t)sbC * 64 + 32 + rhi * 8);

        for (int g = g0; g < nb; g += STEP) {
            short8 nt0, nt1, nh0, nh1;
            bool hasn = (g + STEP) < nb;
            if (hasn) {
                nt0 = *(const short8*)(embB + (size_t)saN * 64 + rhi * 8);
                nt1 = *(const short8*)(embB + (size_t)saN * 64 + 32 + rhi * 8);
                nh0 = *(const short8*)(embB + (size_t)sbN * 64 + rhi * 8);
                nh1 = *(const short8*)(embB + (size_t)sbN * 64 + 32 + rhi * 8);
            }
            if (g + 2 * STEP < nb) ldidx(g + 2 * STEP, saN, sbN);

            f32x4 accT[4], accH[4];
            #pragma unroll
            for (int cb = 0; cb < 4; ++cb) {
                accT[cb] = (f32x4){0.f, 0.f, 0.f, 0.f};
                accH[cb] = (f32x4){0.f, 0.f, 0.f, 0.f};
                accT[cb] = __builtin_amdgcn_mfma_f32_16x16x32_bf16(at0, bfr[cb][0], accT[cb], 0, 0, 0);
                accT[cb] = __builtin_amdgcn_mfma_f32_16x16x32_bf16(at1, bfr[cb][1], accT[cb], 0, 0, 0);
                accH[cb] = __builtin_amdgcn_mfma_f32_16x16x32_bf16(ah0, bfr[cb][0], accH[cb], 0, 0, 0);
                accH[cb] = __builtin_amdgcn_mfma_f32_16x16x32_bf16(ah1, bfr[cb][1], accH[cb], 0, 0, 0);
            }
            int i0 = lo + g * 16;
            #pragma unroll
            for (int i = 0; i < 4; ++i) {
                float s = 0.f;
                #pragma unroll
                for (int cb = 0; cb < 4; ++cb)
                    s += accT[cb][i] * fast_tanh(accH[cb][i] + relv[cb]);
                s += __shfl_xor(s, 1); s += __shfl_xor(s, 2);
                s += __shfl_xor(s, 4); s += __shfl_xor(s, 8);
                int idx = i0 + rhi * 4 + i;
                if (rlo == 0 && idx < hi) att[eperm[idx]] = s;
            }
            at0 = nt0; at1 = nt1; ah0 = nh0; ah1 = nh1;
        }
    } else {
        int bid = blockIdx.x - 4096;       // 3125 blocks
        int c = l & 31, g = l >> 5;
        float Wreg[32];
        #pragma unroll
        for (int kk = 0; kk < 32; ++kk) Wreg[kk] = WLT[(size_t)c * 64 + g * 32 + kk];
        for (int n = bid * 4 + w; n < N_NODES; n += 12500) {
            const float* xr = emb + (size_t)n * 64;
            float v = xr[l];
            #pragma unroll
            for (int r = 0; r < 4; ++r)
                nt_store1(out + (size_t)r * RES + (size_t)n * OUTW + l, v);
            float o = 0.f;
            #pragma unroll
            for (int kk = 0; kk < 32; kk += 4) {
                float4 xv = *(const float4*)(xr + g * 32 + kk);
                o += xv.x * Wreg[kk] + xv.y * Wreg[kk + 1] + xv.z * Wreg[kk + 2] + xv.w * Wreg[kk + 3];
            }
            o += __shfl_xor(o, 32);
            if (l < 32) Y0[(size_t)n * 32 + c] = o;
        }
    }
}

// ---------------- layer 1 with FUSED softmax: raw att in, normalized attn out ----------------
__global__ __launch_bounds__(256) void k_aggF1(const float* __restrict__ Y,
                                               const float* __restrict__ att,
                                               float* __restrict__ attn,
                                               const int* __restrict__ src,
                                               const int* __restrict__ offs,
                                               const float* __restrict__ bias,
                                               const float* __restrict__ WTn,
                                               float* __restrict__ Yn,
                                               float* __restrict__ out) {
    constexpr int D = 32, DN = 16, E = 8, S = 8, KS = 8;
    __shared__ float xm[4][D];
    int tid = threadIdx.x, w = tid >> 6, l = tid & 63;
    int n = blockIdx.x * 4 + w;
    int b = offs[n], e = offs[n + 1];
    int je = l & (E - 1), slot = l / E;
    int c = l & (DN - 1), g = l / DN;

    float Wreg[KS];
    #pragma unroll
    for (int kk = 0; kk < KS; ++kk) Wreg[kk] = WTn[(size_t)c * D + g * KS + kk];

    float m = -INFINITY;
    for (int i = b + l; i < e; i += 64) m = fmaxf(m, att[i]);
    #pragma unroll
    for (int st = 32; st >= 1; st >>= 1) m = fmaxf(m, __shfl_xor(m, st));
    float sum = 0.f;
    for (int i = b + l; i < e; i += 64) sum += __expf(att[i] - m);
    #pragma unroll
    for (int st = 32; st >= 1; st >>= 1) sum += __shfl_xor(sum, st);
    float inv = fast_rcp(sum);

    float4 a = make_float4(0.f, 0.f, 0.f, 0.f);
    int i = b + slot;
    for (; i + S < e; i += 2 * S) {
        float t0 = __expf(att[i] - m) * inv, t1 = __expf(att[i + S] - m) * inv;
        if (je == 0) { attn[i] = t0; attn[i + S] = t1; }
        float4 p0 = *(const float4*)(Y + (size_t)src[i]     * D + 4 * je);
        float4 p1 = *(const float4*)(Y + (size_t)src[i + S] * D + 4 * je);
        a.x += t0 * p0.x + t1 * p1.x;
        a.y += t0 * p0.y + t1 * p1.y;
        a.z += t0 * p0.z + t1 * p1.z;
        a.w += t0 * p0.w + t1 * p1.w;
    }
    for (; i < e; i += S) {
        float t0 = __expf(att[i] - m) * inv;
        if (je == 0) attn[i] = t0;
        float4 p0 = *(const float4*)(Y + (size_t)src[i] * D + 4 * je);
        a.x += t0 * p0.x; a.y += t0 * p0.y; a.z += t0 * p0.z; a.w += t0 * p0.w;
    }
    #pragma unroll
    for (int st = E; st < 64; st <<= 1) {
        a.x += __shfl_xor(a.x, st); a.y += __shfl_xor(a.y, st);
        a.z += __shfl_xor(a.z, st); a.w += __shfl_xor(a.w, st);
    }
    float4 q  = *(const float4*)(Y + (size_t)n * D + 4 * je);
    float4 bi = *(const float4*)(bias + 4 * je);
    float4 u;
    u.x = lrelu(a.x + q.x + bi.x);
    u.y = lrelu(a.y + q.y + bi.y);
    u.z = lrelu(a.z + q.z + bi.z);
    u.w = lrelu(a.w + q.w + bi.w);
    float ss = u.x * u.x + u.y * u.y + u.z * u.z + u.w * u.w;
    #pragma unroll
    for (int st = 1; st < E; st <<= 1) ss += __shfl_xor(ss, st);
    float nv = fast_rcp(fmaxf(sqrtf(ss), 1e-12f));
    if (slot < 4) {
        float4 nr = make_float4(u.x * nv, u.y * nv, u.z * nv, u.w * nv);
        nt_store4(out + (size_t)slot * RES + (size_t)n * OUTW + 64 + 4 * je, nr);
    }
    if (slot == S - 1) *(float4*)&xm[w][4 * je] = u;
    __builtin_amdgcn_s_waitcnt(0);
    __builtin_amdgcn_sched_barrier(0);
    float o = 0.f;
    #pragma unroll
    for (int kk = 0; kk < KS; kk += 4) {
        float4 xv = *(const float4*)&xm[w][g * KS + kk];
        o += xv.x * Wreg[kk] + xv.y * Wreg[kk + 1] + xv.z * Wreg[kk + 2] + xv.w * Wreg[kk + 3];
    }
    #pragma unroll
    for (int st = DN; st < 64; st <<= 1) o += __shfl_xor(o, st);
    if (l < DN) Yn[(size_t)n * DN + c] = o;
}

// ---------------- fused layer (normalized attn in) ----------------
template<int D, int DN, int COL, int RSTART, bool PROJ>
__global__ __launch_bounds__(256) void k_aggF(const float* __restrict__ Y,
                                              const float* __restrict__ att,
                                              const int* __restrict__ src,
                                              const int* __restrict__ offs,
                                              const float* __restrict__ bias,
                                              const float* __restrict__ WTn,
                                              float* __restrict__ Yn,
                                              float* __restrict__ out) {
    constexpr int E = D / 4;
    constexpr int S = 64 / E;
    constexpr int G = PROJ ? (64 / DN) : 1;
    constexpr int KS = PROJ ? (D / G) : 1;
    __shared__ float xm[4][PROJ ? D : 4];
    int tid = threadIdx.x, w = tid >> 6, l = tid & 63;
    int n = blockIdx.x * 4 + w;
    int b = offs[n], e = offs[n + 1];
    int je = l & (E - 1), slot = l / E;

    float Wreg[KS];
    if constexpr (PROJ) {
        int c = l & (DN - 1), g = l / DN;
        #pragma unroll
        for (int kk = 0; kk < KS; ++kk) Wreg[kk] = WTn[(size_t)c * D + g * KS + kk];
    }

    float4 a = make_float4(0.f, 0.f, 0.f, 0.f);
    int i = b + slot;
    for (; i + S < e; i += 2 * S) {
        float t0 = att[i], t1 = att[i + S];
        float4 p0 = *(const float4*)(Y + (size_t)src[i]     * D + 4 * je);
        float4 p1 = *(const float4*)(Y + (size_t)src[i + S] * D + 4 * je);
        a.x += t0 * p0.x + t1 * p1.x;
        a.y += t0 * p0.y + t1 * p1.y;
        a.z += t0 * p0.z + t1 * p1.z;
        a.w += t0 * p0.w + t1 * p1.w;
    }
    for (; i < e; i += S) {
        float t0 = att[i];
        float4 p0 = *(const float4*)(Y + (size_t)src[i] * D + 4 * je);
        a.x += t0 * p0.x; a.y += t0 * p0.y; a.z += t0 * p0.z; a.w += t0 * p0.w;
    }
    #pragma unroll
    for (int st = E; st < 64; st <<= 1) {
        a.x += __shfl_xor(a.x, st); a.y += __shfl_xor(a.y, st);
        a.z += __shfl_xor(a.z, st); a.w += __shfl_xor(a.w, st);
    }
    float4 q  = *(const float4*)(Y + (size_t)n * D + 4 * je);
    float4 bi = *(const float4*)(bias + 4 * je);
    float4 u;
    u.x = lrelu(a.x + q.x + bi.x);
    u.y = lrelu(a.y + q.y + bi.y);
    u.z = lrelu(a.z + q.z + bi.z);
    u.w = lrelu(a.w + q.w + bi.w);
    float ss = u.x * u.x + u.y * u.y + u.z * u.z + u.w * u.w;
    #pragma unroll
    for (int st = 1; st < E; st <<= 1) ss += __shfl_xor(ss, st);
    float inv = fast_rcp(fmaxf(sqrtf(ss), 1e-12f));
    if (slot < 4 - RSTART) {
        float4 nr = make_float4(u.x * inv, u.y * inv, u.z * inv, u.w * inv);
        nt_store4(out + (size_t)(RSTART + slot) * RES + (size_t)n * OUTW + COL + 4 * je, nr);
    }
    if constexpr (PROJ) {
        if (slot == S - 1) *(float4*)&xm[w][4 * je] = u;
        __builtin_amdgcn_s_waitcnt(0);
        __builtin_amdgcn_sched_barrier(0);
        int c = l & (DN - 1), g = l / DN;
        float o = 0.f;
        if constexpr (KS >= 4) {
            #pragma unroll
            for (int kk = 0; kk < KS; kk += 4) {
                float4 xv = *(const float4*)&xm[w][g * KS + kk];
                o += xv.x * Wreg[kk] + xv.y * Wreg[kk + 1] + xv.z * Wreg[kk + 2] + xv.w * Wreg[kk + 3];
            }
        } else {
            float2 xv = *(const float2*)&xm[w][g * KS];
            o += xv.x * Wreg[0] + xv.y * Wreg[1];
        }
        #pragma unroll
        for (int st = DN; st < 64; st <<= 1) o += __shfl_xor(o, st);
        if (l < DN) Yn[(size_t)n * DN + c] = o;
    }
}

// ---------------- merged tail: aggF<8,8,128,3> (blocks 0..24999) + B-chains (25000..43749) ----------------
__global__ __launch_bounds__(256) void k_tail(const float* __restrict__ Y3,
                                              const float* __restrict__ attn,
                                              const int* __restrict__ src,
                                              const int* __restrict__ offs,
                                              const float* __restrict__ b3v,
                                              const float* __restrict__ Y1,
                                              const float* __restrict__ Y2,
                                              const float* __restrict__ WLT,
                                              const float* __restrict__ b1,
                                              const float* __restrict__ b2,
                                              float* __restrict__ out) {
    int tid = threadIdx.x;
    if (blockIdx.x < 25000) {
        constexpr int D = 8, E = 2, S = 32;
        int w = tid >> 6, l = tid & 63;
        int n = blockIdx.x * 4 + w;
        int b = offs[n], e = offs[n + 1];
        int je = l & (E - 1), slot = l / E;
        float4 a = make_float4(0.f, 0.f, 0.f, 0.f);
        int i = b + slot;
        for (; i + S < e; i += 2 * S) {
            float t0 = attn[i], t1 = attn[i + S];
            float4 p0 = *(const float4*)(Y3 + (size_t)src[i]     * D + 4 * je);
            float4 p1 = *(const float4*)(Y3 + (size_t)src[i + S] * D + 4 * je);
            a.x += t0 * p0.x + t1 * p1.x;
            a.y += t0 * p0.y + t1 * p1.y;
            a.z += t0 * p0.z + t1 * p1.z;
            a.w += t0 * p0.w + t1 * p1.w;
        }
        for (; i < e; i += S) {
            float t0 = attn[i];
            float4 p0 = *(const float4*)(Y3 + (size_t)src[i] * D + 4 * je);
            a.x += t0 * p0.x; a.y += t0 * p0.y; a.z += t0 * p0.z; a.w += t0 * p0.w;
        }
        #pragma unroll
        for (int st = E; st < 64; st <<= 1) {
            a.x += __shfl_xor(a.x, st); a.y += __shfl_xor(a.y, st);
            a.z += __shfl_xor(a.z, st); a.w += __shfl_xor(a.w, st);
        }
        float4 q  = *(const float4*)(Y3 + (size_t)n * D + 4 * je);
        float4 bi = *(const float4*)(b3v + 4 * je);
        float4 u;
        u.x = lrelu(a.x + q.x + bi.x);
        u.y = lrelu(a.y + q.y + bi.y);
        u.z = lrelu(a.z + q.z + bi.z);
        u.w = lrelu(a.w + q.w + bi.w);
        float ss = u.x * u.x + u.y * u.y + u.z * u.z + u.w * u.w;
        ss += __shfl_xor(ss, 1);
        float inv = fast_rcp(fmaxf(sqrtf(ss), 1e-12f));
        if (slot < 1) {
            float4 nr = make_float4(u.x * inv, u.y * inv, u.z * inv, u.w * inv);
            nt_store4(out + 3 * RES + (size_t)n * OUTW + 128 + 4 * je, nr);
        }
    } else {
        __shared__ float W2s[16][17], W3s[8][17];
        __shared__ float bb1[16], bb2[16], bb3[8];
        __shared__ float mid[16][17], mid2[16][17];
        if (tid < 256) W2s[tid >> 4][tid & 15] = WLT[2560 + tid];
        if (tid < 128) W3s[tid >> 4][tid & 15] = WLT[2816 + tid];
        if (tid < 16) bb1[tid] = b1[tid];
        if (tid >= 32 && tid < 48) bb2[tid - 32] = b2[tid - 32];
        if (tid >= 64 && tid < 72) bb3[tid - 64] = b3v[tid - 64];
        __syncthreads();

        int grp = tid >> 4, lj = tid & 15;
        int bid = blockIdx.x - 25000;
        int seg = bid / 6250;
        int nb = bid % 6250;
        int n = nb * 16 + grp;

        if (seg == 0) {
            float u1 = lrelu(Y1[(size_t)n * 16 + lj] + bb1[lj]);
            mid[grp][lj] = u1;
            float ss = u1 * u1;
            #pragma unroll
            for (int m = 8; m >= 1; m >>= 1) ss += __shfl_xor(ss, m);
            nt_store1(out + (size_t)n * OUTW + 96 + lj, u1 * fast_rcp(fmaxf(sqrtf(ss), 1e-12f)));
            __builtin_amdgcn_s_waitcnt(0);
            __builtin_amdgcn_sched_barrier(0);
            float o2 = bb2[lj];
            #pragma unroll
            for (int k = 0; k < 16; ++k) o2 += mid[grp][k] * W2s[lj][k];
            float u2 = lrelu(o2);
            mid2[grp][lj] = u2;
            float s2 = u2 * u2;
            #pragma unroll
            for (int m = 8; m >= 1; m >>= 1) s2 += __shfl_xor(s2, m);
            nt_store1(out + (size_t)n * OUTW + 112 + lj, u2 * fast_rcp(fmaxf(sqrtf(s2), 1e-12f)));
            __builtin_amdgcn_s_waitcnt(0);
            __builtin_amdgcn_sched_barrier(0);
            if (lj < 8) {
                float o3 = bb3[lj];
                #pragma unroll
                for (int k = 0; k < 16; ++k) o3 += mid2[grp][k] * W3s[lj][k];
                float u3 = lrelu(o3);
                float s3 = u3 * u3;
                #pragma unroll
                for (int m = 4; m >= 1; m >>= 1) s3 += __shfl_xor(s3, m);
                nt_store1(out + (size_t)n * OUTW + 128 + lj, u3 * fast_rcp(fmaxf(sqrtf(s3), 1e-12f)));
            }
        } else if (seg == 1) {
            float u2 = lrelu(Y2[(size_t)n * 16 + lj] + bb2[lj]);
            mid[grp][lj] = u2;
            float s2 = u2 * u2;
            #pragma unroll
            for (int m = 8; m >= 1; m >>= 1) s2 += __shfl_xor(s2, m);
            nt_store1(out + RES + (size_t)n * OUTW + 112 + lj, u2 * fast_rcp(fmaxf(sqrtf(s2), 1e-12f)));
            __builtin_amdgcn_s_waitcnt(0);
            __builtin_amdgcn_sched_barrier(0);
            if (lj < 8) {
                float o3 = bb3[lj];
                #pragma unroll
                for (int k = 0; k < 16; ++k) o3 += mid[grp][k] * W3s[lj][k];
                float u3 = lrelu(o3);
                float s3 = u3 * u3;
                #pragma unroll
                for (int m = 4; m >= 1; m >>= 1) s3 += __shfl_xor(s3, m);
                nt_store1(out + RES + (size_t)n * OUTW + 128 + lj, u3 * fast_rcp(fmaxf(sqrtf(s3), 1e-12f)));
            }
        } else {
            if (lj < 8) {
                float u3 = lrelu(Y3[(size_t)n * 8 + lj] + bb3[lj]);
                float s3 = u3 * u3;
                #pragma unroll
                for (int m = 4; m >= 1; m >>= 1) s3 += __shfl_xor(s3, m);
                nt_store1(out + 2 * RES + (size_t)n * OUTW + 128 + lj, u3 * fast_rcp(fmaxf(sqrtf(s3), 1e-12f)));
            }
        }
    }
}

extern "C" void kernel_launch(void* const* d_in, const int* in_sizes, int n_in,
                              void* d_out, int out_size, void* d_ws, size_t ws_size,
                              hipStream_t stream) {
    (void)in_sizes; (void)n_in; (void)out_size; (void)ws_size;
    const float* emb = (const float*)d_in[0];
    const float* rel_embed = (const float*)d_in[1];
    const float* W_R = (const float*)d_in[2];
    const float* W0 = (const float*)d_in[3];  const float* b0 = (const float*)d_in[4];
    const float* W1 = (const float*)d_in[5];  const float* b1 = (const float*)d_in[6];
    const float* W2 = (const float*)d_in[7];  const float* b2 = (const float*)d_in[8];
    const float* W3 = (const float*)d_in[9];  const float* b3 = (const float*)d_in[10];
    const int* src = (const int*)d_in[11];
    const int* dst = (const int*)d_in[12];
    const int* etype = (const int*)d_in[13];
    float* out = (float*)d_out;

    char* p = (char*)d_ws;
    auto alloc = [&](size_t bytes) { char* q = p; p += (bytes + 255) & ~(size_t)255; return q; };
    int* offs  = (int*)alloc((size_t)(N_NODES + 1) * 4);
    float* att = (float*)alloc((size_t)N_EDGES * 4);
    float* attn = (float*)alloc((size_t)N_EDGES * 4);
    int* eperm = (int*)alloc((size_t)N_EDGES * 4);
    int* srcp  = (int*)alloc((size_t)N_EDGES * 4);
    int* dstp  = (int*)alloc((size_t)N_EDGES * 4);
    int* cnt   = (int*)alloc(64);
    int* roff  = (int*)alloc(68);
    int* cur   = (int*)alloc(64);
    unsigned short* embB = (unsigned short*)alloc((size_t)N_NODES * 64 * 2);
    unsigned short* WT   = (unsigned short*)alloc((size_t)65536 * 2);
    float* WLT = (float*)alloc((size_t)2944 * 4);
    float* Y0  = (float*)alloc((size_t)N_NODES * 32 * 4);
    float* Y1  = (float*)alloc((size_t)N_NODES * 16 * 4);
    float* Y2  = (float*)alloc((size_t)N_NODES * 16 * 4);
    float* Y3  = (float*)alloc((size_t)N_NODES * 8 * 4);

    (void)hipMemsetAsync(cnt, 0, 64, stream);
    // fused prep (cast emb, W_R^T, W^T, CSR offsets, etype hist)
    k_prep<<<13159, 256, 0, stream>>>(emb, embB, W_R, WT, W0, W1, W2, W3, WLT, dst, offs, etype, cnt);
    k_scan<<<1, 64, 0, stream>>>(cnt, roff, cur);
    k_scatter<<<N_EDGES / 256, 256, 0, stream>>>(etype, src, dst, cur, eperm, srcp, dstp);

    // attention (4096 blocks, 256/relation) + dense0/emb-copy (3125 blocks) in one dispatch
    k_att_dense<<<4096 + 3125, 256, 0, stream>>>(embB, WT, rel_embed, srcp, dstp, eperm, roff, att,
                                                 emb, WLT, Y0, out);

    // layer 1 with fused softmax (writes normalized attn for layers 2-4)
    k_aggF1<<<N_NODES / 4, 256, 0, stream>>>(Y0, att, attn, src, offs, b0, WLT + 2048, Y1, out);
    k_aggF<16, 16,  96, 1, true ><<<N_NODES / 4, 256, 0, stream>>>(Y1, attn, src, offs, b1, WLT + 2560, Y2, out);
    k_aggF<16,  8, 112, 2, true ><<<N_NODES / 4, 256, 0, stream>>>(Y2, attn, src, offs, b2, WLT + 2816, Y3, out);

    // last aggregation layer + all B-chains in one dispatch
    k_tail<<<25000 + 18750, 256, 0, stream>>>(Y3, attn, src, offs, b3, Y1, Y2, WLT, b1, b2, out);
}